// Round 7
// baseline (2513.592 us; speedup 1.0000x reference)
//
#include <hip/hip_runtime.h>
#include <hip/hip_bf16.h>

#define N_NODES 100000
#define N_EDGES 1000000
#define DIM 64

static const long long ND = (long long)N_NODES * DIM;  // 6,400,000

typedef float f4_t __attribute__((ext_vector_type(4)));

// d_out layout (floats):
// h1: [0, ND)  h2: [ND, 2*ND)  c1c2: [2*ND, 2*ND+128)  h3: [2*ND+128, ...)  h4: [3*ND+128, ...)

// d_ws layout (4-byte words, all region bases %4 == 0 for int4/uint4 access):
#define WS_CUR1  0
#define WS_CUR2  100000
#define WS_OFF1  200000            // 100001 used, padded to 100004
#define WS_OFF2  300004
#define WS_SORT1 400008
#define WS_SORT2 1400008
#define WS_CSUM  2400008           // 128 floats
#define WS_BSUM  2400136           // 196 ints (2 graphs x 98 blocks)
#define WS_T1    2400512           // bf16 [G|S] rows, 64 words/row, 6.4M words
#define WS_T2    (WS_T1 + 6400000)
#define WS_END   (WS_T2 + 6400000) // 15,200,512 words = ~58 MB

#define SCAN_BLOCKS 98             // 98 * 1024 >= 100000

// fused fill+transform grid: groups of 7 blocks = 5 fill + 2 transform
#define FT_GROUPS 391              // fill: 391*5=1955>=1954; trans: 391*2=782
#define FT_BLOCKS (FT_GROUPS * 7)

__device__ __forceinline__ unsigned pk_bf16(float a, float b) {
    __hip_bfloat16 ha = __float2bfloat16(a), hb = __float2bfloat16(b);
    return (unsigned)(*(unsigned short*)&ha) | ((unsigned)(*(unsigned short*)&hb) << 16);
}
__device__ __forceinline__ float bf_lo(unsigned u) { return __uint_as_float(u << 16); }
__device__ __forceinline__ float bf_hi(unsigned u) { return __uint_as_float(u & 0xFFFF0000u); }

__global__ __launch_bounds__(256) void k_init(int* __restrict__ ws) {
    int i = blockIdx.x * blockDim.x + threadIdx.x;
    if (i < 200000) ws[i] = 0;                                   // cursors (= histograms)
    else if (i < 200128) ((float*)ws)[WS_CSUM + (i - 200000)] = 0.f;
    else if (i == 200128) {
        ws[WS_OFF1 + N_NODES] = N_EDGES;
        ws[WS_OFF2 + N_NODES] = N_EDGES;
    }
}

__global__ __launch_bounds__(256) void k_hist(const int4* __restrict__ dst1,
                                              const int4* __restrict__ dst2,
                                              int* __restrict__ ws) {
    int i = blockIdx.x * blockDim.x + threadIdx.x;
    const int Q = N_EDGES / 4;
    if (i < Q) {
        int4 d = dst1[i];
        atomicAdd(&ws[WS_CUR1 + d.x], 1);
        atomicAdd(&ws[WS_CUR1 + d.y], 1);
        atomicAdd(&ws[WS_CUR1 + d.z], 1);
        atomicAdd(&ws[WS_CUR1 + d.w], 1);
    } else if (i < 2 * Q) {
        int4 d = dst2[i - Q];
        atomicAdd(&ws[WS_CUR2 + d.x], 1);
        atomicAdd(&ws[WS_CUR2 + d.y], 1);
        atomicAdd(&ws[WS_CUR2 + d.z], 1);
        atomicAdd(&ws[WS_CUR2 + d.w], 1);
    }
}

// Phase 1: per-block sums of 1024 counts -> bsum[g*98+b]
__global__ __launch_bounds__(256) void k_scan1(int* __restrict__ ws) {
    const int g = blockIdx.y;
    const int* hist = ws + (g ? WS_CUR2 : WS_CUR1);
    const int t = threadIdx.x;
    const int base = blockIdx.x * 1024 + t * 4;
    int4 c = make_int4(0, 0, 0, 0);
    if (base < N_NODES) c = *(const int4*)(hist + base);
    __shared__ int s[256];
    s[t] = c.x + c.y + c.z + c.w;
    __syncthreads();
    for (int d = 128; d > 0; d >>= 1) {
        if (t < d) s[t] += s[t + d];
        __syncthreads();
    }
    if (t == 0) ws[WS_BSUM + g * SCAN_BLOCKS + blockIdx.x] = s[0];
}

// Phase 2: one block scans the 196 block sums (two independent 98-segments), exclusive.
__global__ __launch_bounds__(256) void k_scan2(int* __restrict__ ws) {
    const int t = threadIdx.x;
    const int n = 2 * SCAN_BLOCKS;
    __shared__ int s[256];
    s[t] = (t < n) ? ws[WS_BSUM + t] : 0;
    __syncthreads();
    for (int d = 1; d < 256; d <<= 1) {
        int v = 0;
        if (t >= d && (t < SCAN_BLOCKS || t - d >= SCAN_BLOCKS)) v = s[t - d];
        __syncthreads();
        s[t] += v;
        __syncthreads();
    }
    if (t < n) {
        int excl = (t == 0 || t == SCAN_BLOCKS) ? 0 : s[t - 1];
        ws[WS_BSUM + t] = excl;
    }
}

// Phase 3: local exclusive scan + block offset -> off[] and cursor[]
__global__ __launch_bounds__(256) void k_scan3(int* __restrict__ ws) {
    const int g = blockIdx.y;
    int* cur = ws + (g ? WS_CUR2 : WS_CUR1);
    int* off = ws + (g ? WS_OFF2 : WS_OFF1);
    const int t = threadIdx.x;
    const int base = blockIdx.x * 1024 + t * 4;
    int4 c = make_int4(0, 0, 0, 0);
    if (base < N_NODES) c = *(const int4*)(cur + base);
    __shared__ int s[256];
    s[t] = c.x + c.y + c.z + c.w;
    __syncthreads();
    for (int d = 1; d < 256; d <<= 1) {
        int v = 0;
        if (t >= d) v = s[t - d];
        __syncthreads();
        s[t] += v;
        __syncthreads();
    }
    int excl = (t == 0) ? 0 : s[t - 1];
    int boff = ws[WS_BSUM + g * SCAN_BLOCKS + blockIdx.x];
    if (base < N_NODES) {
        int o0 = boff + excl;
        int o1 = o0 + c.x, o2 = o1 + c.y, o3 = o2 + c.z;
        int4 o = make_int4(o0, o1, o2, o3);
        *(int4*)(off + base) = o;
        *(int4*)(cur + base) = o;
    }
}

// FUSED fill + transform. Block-uniform role split: per group of 7 blocks,
// r<2 -> transform (782 blocks), r>=2 -> fill (1955 blocks).
// Fill is HBM-random-write bound (VALU ~0%); transform is VALU-bound -> overlap.
// Transform: thread per (node, branch): a[64] + 16 acc => ~100 VGPR (vs 256 fused-both).
__global__ __launch_bounds__(256, 4) void k_fill_transform(
    const int4* __restrict__ src1, const int4* __restrict__ dst1,
    const int4* __restrict__ src2, const int4* __restrict__ dst2,
    int* __restrict__ ws,
    const float* __restrict__ feat, const float* __restrict__ shuf,
    const float* __restrict__ W1, const float* __restrict__ W2) {
    __shared__ float Wl[2][64 * 64];
    const int bid = blockIdx.x;
    const int grp = bid / 7;
    const int r = bid - grp * 7;
    const int t = threadIdx.x;

    if (r < 2) {
        // ---------------- transform ----------------
        for (int i = t; i < 64 * 64; i += 256) {
            Wl[0][i] = W1[i];
            Wl[1][i] = W2[i];
        }
        __syncthreads();

        const int gid = (grp * 2 + r) * 256 + t;
        if (gid >= 2 * N_NODES) return;
        const int br = gid >= N_NODES;
        const int n = br ? gid - N_NODES : gid;
        const float* srcp = br ? shuf : feat;

        float a[64];
        const f4_t* a4 = (const f4_t*)(srcp + (long long)n * DIM);
        #pragma unroll
        for (int i = 0; i < 16; ++i) {
            f4_t v = __builtin_nontemporal_load(a4 + i);
            a[4 * i + 0] = v.x; a[4 * i + 1] = v.y;
            a[4 * i + 2] = v.z; a[4 * i + 3] = v.w;
        }

        uint4* T1row = (uint4*)(ws + WS_T1) + (long long)n * 16 + br * 8;
        uint4* T2row = (uint4*)(ws + WS_T2) + (long long)n * 16 + br * 8;
        const float4* W14 = (const float4*)Wl[0];
        const float4* W24 = (const float4*)Wl[1];

        #pragma unroll
        for (int jb = 0; jb < 8; ++jb) {
            float f1[8] = {0,0,0,0,0,0,0,0};
            float f2[8] = {0,0,0,0,0,0,0,0};
            #pragma unroll
            for (int k = 0; k < 64; ++k) {
                const float4 wa = W14[k * 16 + jb * 2];
                const float4 wb = W14[k * 16 + jb * 2 + 1];
                const float4 va = W24[k * 16 + jb * 2];
                const float4 vb = W24[k * 16 + jb * 2 + 1];
                const float ak = a[k];
                f1[0] += ak * wa.x; f1[1] += ak * wa.y; f1[2] += ak * wa.z; f1[3] += ak * wa.w;
                f1[4] += ak * wb.x; f1[5] += ak * wb.y; f1[6] += ak * wb.z; f1[7] += ak * wb.w;
                f2[0] += ak * va.x; f2[1] += ak * va.y; f2[2] += ak * va.z; f2[3] += ak * va.w;
                f2[4] += ak * vb.x; f2[5] += ak * vb.y; f2[6] += ak * vb.z; f2[7] += ak * vb.w;
            }
            uint4 p;
            p.x = pk_bf16(f1[0], f1[1]); p.y = pk_bf16(f1[2], f1[3]);
            p.z = pk_bf16(f1[4], f1[5]); p.w = pk_bf16(f1[6], f1[7]);
            T1row[jb] = p;
            p.x = pk_bf16(f2[0], f2[1]); p.y = pk_bf16(f2[2], f2[3]);
            p.z = pk_bf16(f2[4], f2[5]); p.w = pk_bf16(f2[6], f2[7]);
            T2row[jb] = p;
        }
    } else {
        // ---------------- fill ----------------
        const int i = (grp * 5 + (r - 2)) * 256 + t;
        const int Q = N_EDGES / 4;
        if (i < Q) {
            int4 sv = src1[i]; int4 dv = dst1[i];
            int p0 = atomicAdd(&ws[WS_CUR1 + dv.x], 1); ws[WS_SORT1 + p0] = sv.x;
            int p1 = atomicAdd(&ws[WS_CUR1 + dv.y], 1); ws[WS_SORT1 + p1] = sv.y;
            int p2 = atomicAdd(&ws[WS_CUR1 + dv.z], 1); ws[WS_SORT1 + p2] = sv.z;
            int p3 = atomicAdd(&ws[WS_CUR1 + dv.w], 1); ws[WS_SORT1 + p3] = sv.w;
        } else if (i < 2 * Q) {
            int e = i - Q;
            int4 sv = src2[e]; int4 dv = dst2[e];
            int p0 = atomicAdd(&ws[WS_CUR2 + dv.x], 1); ws[WS_SORT2 + p0] = sv.x;
            int p1 = atomicAdd(&ws[WS_CUR2 + dv.y], 1); ws[WS_SORT2 + p1] = sv.y;
            int p2 = atomicAdd(&ws[WS_CUR2 + dv.z], 1); ws[WS_SORT2 + p2] = sv.z;
            int p3 = atomicAdd(&ws[WS_CUR2 + dv.w], 1); ws[WS_SORT2 + p3] = sv.w;
        }
    }
}

// Gather-aggregate, one graph per dispatch. 4 waves/block, 8 nodes/wave serial.
// 8 edge-slots x 8 lanes/edge; each lane loads the G-chunk AND S-chunk (2 x 16B).
__global__ __launch_bounds__(256) void k_gather_pre(const int* __restrict__ off,
                                                    const int* __restrict__ sorted,
                                                    const uint4* __restrict__ T,
                                                    const float* __restrict__ bias,
                                                    float* __restrict__ h_f,
                                                    float* __restrict__ h_s,
                                                    float* __restrict__ csum) {
    const int t = threadIdx.x;
    const int wave = t >> 6;
    const int lane = t & 63;
    const int slot = lane >> 3;
    const int sub = lane & 7;

    float bias8[8];
    #pragma unroll
    for (int i = 0; i < 8; ++i) bias8[i] = bias[sub * 8 + i];

    __shared__ float red[4][8][8];
    float csum_acc[8] = {0.f, 0.f, 0.f, 0.f, 0.f, 0.f, 0.f, 0.f};

    const int nb = blockIdx.x * 32 + wave * 8;
    for (int r = 0; r < 8; ++r) {
        const int n = nb + r;
        if (n >= N_NODES) break;
        const int e0 = off[n];
        const int e1 = off[n + 1];

        float ag[8] = {0.f, 0.f, 0.f, 0.f, 0.f, 0.f, 0.f, 0.f};
        float as[8] = {0.f, 0.f, 0.f, 0.f, 0.f, 0.f, 0.f, 0.f};
        int e = e0 + slot;
        for (; e + 8 < e1; e += 16) {
            const int sA = sorted[e];
            const int sB = sorted[e + 8];
            const uint4 gA = T[sA * 16 + sub];
            const uint4 sAv = T[sA * 16 + 8 + sub];
            const uint4 gB = T[sB * 16 + sub];
            const uint4 sBv = T[sB * 16 + 8 + sub];
            ag[0] += bf_lo(gA.x); ag[1] += bf_hi(gA.x);
            ag[2] += bf_lo(gA.y); ag[3] += bf_hi(gA.y);
            ag[4] += bf_lo(gA.z); ag[5] += bf_hi(gA.z);
            ag[6] += bf_lo(gA.w); ag[7] += bf_hi(gA.w);
            as[0] += bf_lo(sAv.x); as[1] += bf_hi(sAv.x);
            as[2] += bf_lo(sAv.y); as[3] += bf_hi(sAv.y);
            as[4] += bf_lo(sAv.z); as[5] += bf_hi(sAv.z);
            as[6] += bf_lo(sAv.w); as[7] += bf_hi(sAv.w);
            ag[0] += bf_lo(gB.x); ag[1] += bf_hi(gB.x);
            ag[2] += bf_lo(gB.y); ag[3] += bf_hi(gB.y);
            ag[4] += bf_lo(gB.z); ag[5] += bf_hi(gB.z);
            ag[6] += bf_lo(gB.w); ag[7] += bf_hi(gB.w);
            as[0] += bf_lo(sBv.x); as[1] += bf_hi(sBv.x);
            as[2] += bf_lo(sBv.y); as[3] += bf_hi(sBv.y);
            as[4] += bf_lo(sBv.z); as[5] += bf_hi(sBv.z);
            as[6] += bf_lo(sBv.w); as[7] += bf_hi(sBv.w);
        }
        if (e < e1) {
            const int s = sorted[e];
            const uint4 gv = T[s * 16 + sub];
            const uint4 sv = T[s * 16 + 8 + sub];
            ag[0] += bf_lo(gv.x); ag[1] += bf_hi(gv.x);
            ag[2] += bf_lo(gv.y); ag[3] += bf_hi(gv.y);
            ag[4] += bf_lo(gv.z); ag[5] += bf_hi(gv.z);
            ag[6] += bf_lo(gv.w); ag[7] += bf_hi(gv.w);
            as[0] += bf_lo(sv.x); as[1] += bf_hi(sv.x);
            as[2] += bf_lo(sv.y); as[3] += bf_hi(sv.y);
            as[4] += bf_lo(sv.z); as[5] += bf_hi(sv.z);
            as[6] += bf_lo(sv.w); as[7] += bf_hi(sv.w);
        }
        #pragma unroll
        for (int i = 0; i < 8; ++i) {
            ag[i] += __shfl_xor(ag[i], 8);
            ag[i] += __shfl_xor(ag[i], 16);
            ag[i] += __shfl_xor(ag[i], 32);
            as[i] += __shfl_xor(as[i], 8);
            as[i] += __shfl_xor(as[i], 16);
            as[i] += __shfl_xor(as[i], 32);
            ag[i] += bias8[i];
            as[i] += bias8[i];
        }
        if (slot == 0) {
            float* p = h_f + (long long)n * DIM + sub * 8;
            f4_t v0 = {ag[0], ag[1], ag[2], ag[3]};
            f4_t v1 = {ag[4], ag[5], ag[6], ag[7]};
            __builtin_nontemporal_store(v0, (f4_t*)p);
            __builtin_nontemporal_store(v1, (f4_t*)(p + 4));
            #pragma unroll
            for (int i = 0; i < 8; ++i) csum_acc[i] += ag[i];
        } else if (slot == 1) {
            float* p = h_s + (long long)n * DIM + sub * 8;
            f4_t v0 = {as[0], as[1], as[2], as[3]};
            f4_t v1 = {as[4], as[5], as[6], as[7]};
            __builtin_nontemporal_store(v0, (f4_t*)p);
            __builtin_nontemporal_store(v1, (f4_t*)(p + 4));
        }
    }

    if (slot == 0) {
        #pragma unroll
        for (int i = 0; i < 8; ++i) red[wave][sub][i] = csum_acc[i];
    }
    __syncthreads();
    if (t < 64) {
        int su = t >> 3, i = t & 7;
        float s4 = red[0][su][i] + red[1][su][i] + red[2][su][i] + red[3][su][i];
        unsafeAtomicAdd(&csum[su * 8 + i], s4);
    }
}

__global__ void k_final(const float* __restrict__ ws_csum, float* __restrict__ out_c) {
    int t = threadIdx.x;  // 0..63 -> c1, 64..127 -> c2
    float m = ws_csum[t] * (1.0f / (float)N_NODES);
    out_c[t] = 1.f / (1.f + expf(-m));
}

extern "C" void kernel_launch(void* const* d_in, const int* in_sizes, int n_in,
                              void* d_out, int out_size, void* d_ws, size_t ws_size,
                              hipStream_t stream) {
    const float* feat = (const float*)d_in[0];
    const float* shuf = (const float*)d_in[1];
    const int* src1 = (const int*)d_in[2];
    const int* dst1 = (const int*)d_in[3];
    const int* src2 = (const int*)d_in[4];
    const int* dst2 = (const int*)d_in[5];
    const float* W1 = (const float*)d_in[6];
    const float* b1 = (const float*)d_in[7];
    const float* W2 = (const float*)d_in[8];
    const float* b2 = (const float*)d_in[9];

    float* out = (float*)d_out;
    int* ws = (int*)d_ws;
    float* ws_f = (float*)d_ws;
    float* c_out = out + 2 * ND;

    k_init<<<(200129 + 255) / 256, 256, 0, stream>>>(ws);
    k_hist<<<(2 * (N_EDGES / 4) + 255) / 256, 256, 0, stream>>>(
        (const int4*)dst1, (const int4*)dst2, ws);
    k_scan1<<<dim3(SCAN_BLOCKS, 2), 256, 0, stream>>>(ws);
    k_scan2<<<1, 256, 0, stream>>>(ws);
    k_scan3<<<dim3(SCAN_BLOCKS, 2), 256, 0, stream>>>(ws);

    k_fill_transform<<<FT_BLOCKS, 256, 0, stream>>>(
        (const int4*)src1, (const int4*)dst1, (const int4*)src2, (const int4*)dst2,
        ws, feat, shuf, W1, W2);

    const int ggrid = (N_NODES + 31) / 32;
    k_gather_pre<<<ggrid, 256, 0, stream>>>(
        ws + WS_OFF1, ws + WS_SORT1, (const uint4*)(ws + WS_T1), b1,
        out, out + 2 * ND + 128, ws_f + WS_CSUM);
    k_gather_pre<<<ggrid, 256, 0, stream>>>(
        ws + WS_OFF2, ws + WS_SORT2, (const uint4*)(ws + WS_T2), b2,
        out + ND, out + 3 * ND + 128, ws_f + WS_CSUM + 64);

    k_final<<<1, 128, 0, stream>>>(ws_f + WS_CSUM, c_out);
}

// Round 8
// 478.779 us; speedup vs baseline: 5.2500x; 5.2500x over previous
//
#include <hip/hip_runtime.h>
#include <hip/hip_bf16.h>

#define N_NODES 100000
#define N_EDGES 1000000
#define DIM 64

static const long long ND = (long long)N_NODES * DIM;  // 6,400,000

typedef float f4_t __attribute__((ext_vector_type(4)));

// d_out layout (floats):
// h1: [0, ND)  h2: [ND, 2*ND)  c1c2: [2*ND, 2*ND+128)  h3: [2*ND+128, ...)  h4: [3*ND+128, ...)

// d_ws layout (4-byte words, all region bases %4 == 0 for int4/uint4 access):
#define WS_CUR1  0
#define WS_CUR2  100000
#define WS_OFF1  200000            // 100001 used, padded to 100004
#define WS_OFF2  300004
#define WS_SORT1 400008
#define WS_SORT2 1400008
#define WS_CSUM  2400008           // 128 floats
#define WS_BSUM  2400136           // 196 ints (2 graphs x 98 blocks)
#define WS_T1    2400512           // bf16 [G|S] rows, 64 words/row, 6.4M words
#define WS_T2    (WS_T1 + 6400000)
#define WS_END   (WS_T2 + 6400000) // 15,200,512 words = ~58 MB

#define SCAN_BLOCKS 98             // 98 * 1024 >= 100000

// fused fill+transform grid: groups of 7 blocks = 5 fill + 2 transform
#define FT_GROUPS 391              // fill: 391*5=1955>=1954; trans: 391*2=782
#define FT_BLOCKS (FT_GROUPS * 7)

__device__ __forceinline__ unsigned pk_bf16(float a, float b) {
    __hip_bfloat16 ha = __float2bfloat16(a), hb = __float2bfloat16(b);
    return (unsigned)(*(unsigned short*)&ha) | ((unsigned)(*(unsigned short*)&hb) << 16);
}
__device__ __forceinline__ float bf_lo(unsigned u) { return __uint_as_float(u << 16); }
__device__ __forceinline__ float bf_hi(unsigned u) { return __uint_as_float(u & 0xFFFF0000u); }

__global__ __launch_bounds__(256) void k_init(int* __restrict__ ws) {
    int i = blockIdx.x * blockDim.x + threadIdx.x;
    if (i < 200000) ws[i] = 0;                                   // cursors (= histograms)
    else if (i < 200128) ((float*)ws)[WS_CSUM + (i - 200000)] = 0.f;
    else if (i == 200128) {
        ws[WS_OFF1 + N_NODES] = N_EDGES;
        ws[WS_OFF2 + N_NODES] = N_EDGES;
    }
}

__global__ __launch_bounds__(256) void k_hist(const int4* __restrict__ dst1,
                                              const int4* __restrict__ dst2,
                                              int* __restrict__ ws) {
    int i = blockIdx.x * blockDim.x + threadIdx.x;
    const int Q = N_EDGES / 4;
    if (i < Q) {
        int4 d = dst1[i];
        atomicAdd(&ws[WS_CUR1 + d.x], 1);
        atomicAdd(&ws[WS_CUR1 + d.y], 1);
        atomicAdd(&ws[WS_CUR1 + d.z], 1);
        atomicAdd(&ws[WS_CUR1 + d.w], 1);
    } else if (i < 2 * Q) {
        int4 d = dst2[i - Q];
        atomicAdd(&ws[WS_CUR2 + d.x], 1);
        atomicAdd(&ws[WS_CUR2 + d.y], 1);
        atomicAdd(&ws[WS_CUR2 + d.z], 1);
        atomicAdd(&ws[WS_CUR2 + d.w], 1);
    }
}

// Phase 1: per-block sums of 1024 counts -> bsum[g*98+b]
__global__ __launch_bounds__(256) void k_scan1(int* __restrict__ ws) {
    const int g = blockIdx.y;
    const int* hist = ws + (g ? WS_CUR2 : WS_CUR1);
    const int t = threadIdx.x;
    const int base = blockIdx.x * 1024 + t * 4;
    int4 c = make_int4(0, 0, 0, 0);
    if (base < N_NODES) c = *(const int4*)(hist + base);
    __shared__ int s[256];
    s[t] = c.x + c.y + c.z + c.w;
    __syncthreads();
    for (int d = 128; d > 0; d >>= 1) {
        if (t < d) s[t] += s[t + d];
        __syncthreads();
    }
    if (t == 0) ws[WS_BSUM + g * SCAN_BLOCKS + blockIdx.x] = s[0];
}

// Phase 2: one block scans the 196 block sums (two independent 98-segments), exclusive.
__global__ __launch_bounds__(256) void k_scan2(int* __restrict__ ws) {
    const int t = threadIdx.x;
    const int n = 2 * SCAN_BLOCKS;
    __shared__ int s[256];
    s[t] = (t < n) ? ws[WS_BSUM + t] : 0;
    __syncthreads();
    for (int d = 1; d < 256; d <<= 1) {
        int v = 0;
        if (t >= d && (t < SCAN_BLOCKS || t - d >= SCAN_BLOCKS)) v = s[t - d];
        __syncthreads();
        s[t] += v;
        __syncthreads();
    }
    if (t < n) {
        int excl = (t == 0 || t == SCAN_BLOCKS) ? 0 : s[t - 1];
        ws[WS_BSUM + t] = excl;
    }
}

// Phase 3: local exclusive scan + block offset -> off[] and cursor[]
__global__ __launch_bounds__(256) void k_scan3(int* __restrict__ ws) {
    const int g = blockIdx.y;
    int* cur = ws + (g ? WS_CUR2 : WS_CUR1);
    int* off = ws + (g ? WS_OFF2 : WS_OFF1);
    const int t = threadIdx.x;
    const int base = blockIdx.x * 1024 + t * 4;
    int4 c = make_int4(0, 0, 0, 0);
    if (base < N_NODES) c = *(const int4*)(cur + base);
    __shared__ int s[256];
    s[t] = c.x + c.y + c.z + c.w;
    __syncthreads();
    for (int d = 1; d < 256; d <<= 1) {
        int v = 0;
        if (t >= d) v = s[t - d];
        __syncthreads();
        s[t] += v;
        __syncthreads();
    }
    int excl = (t == 0) ? 0 : s[t - 1];
    int boff = ws[WS_BSUM + g * SCAN_BLOCKS + blockIdx.x];
    if (base < N_NODES) {
        int o0 = boff + excl;
        int o1 = o0 + c.x, o2 = o1 + c.y, o3 = o2 + c.z;
        int4 o = make_int4(o0, o1, o2, o3);
        *(int4*)(off + base) = o;
        *(int4*)(cur + base) = o;
    }
}

// FUSED fill + transform. Block-uniform role split: per group of 7 blocks,
// r<2 -> transform (782 blocks), r>=2 -> fill (1955 blocks).
// NOTE: no min-waves in launch_bounds! R7's (256,4) capped VGPR at 64 and the
// transform path (a[64]+16acc) spilled ~7GB of scratch traffic per dispatch.
__global__ __launch_bounds__(256) void k_fill_transform(
    const int4* __restrict__ src1, const int4* __restrict__ dst1,
    const int4* __restrict__ src2, const int4* __restrict__ dst2,
    int* __restrict__ ws,
    const float* __restrict__ feat, const float* __restrict__ shuf,
    const float* __restrict__ W1, const float* __restrict__ W2) {
    __shared__ float Wl[2][64 * 64];
    const int bid = blockIdx.x;
    const int grp = bid / 7;
    const int r = bid - grp * 7;
    const int t = threadIdx.x;

    if (r < 2) {
        // ---------------- transform: thread per (node, branch) ----------------
        for (int i = t; i < 64 * 64; i += 256) {
            Wl[0][i] = W1[i];
            Wl[1][i] = W2[i];
        }
        __syncthreads();

        const int gid = (grp * 2 + r) * 256 + t;
        if (gid >= 2 * N_NODES) return;
        const int br = gid >= N_NODES;
        const int n = br ? gid - N_NODES : gid;
        const float* srcp = br ? shuf : feat;

        float a[64];
        const f4_t* a4 = (const f4_t*)(srcp + (long long)n * DIM);
        #pragma unroll
        for (int i = 0; i < 16; ++i) {
            f4_t v = __builtin_nontemporal_load(a4 + i);
            a[4 * i + 0] = v.x; a[4 * i + 1] = v.y;
            a[4 * i + 2] = v.z; a[4 * i + 3] = v.w;
        }

        uint4* T1row = (uint4*)(ws + WS_T1) + (long long)n * 16 + br * 8;
        uint4* T2row = (uint4*)(ws + WS_T2) + (long long)n * 16 + br * 8;
        const float4* W14 = (const float4*)Wl[0];
        const float4* W24 = (const float4*)Wl[1];

        #pragma unroll
        for (int jb = 0; jb < 8; ++jb) {
            float f1[8] = {0,0,0,0,0,0,0,0};
            float f2[8] = {0,0,0,0,0,0,0,0};
            #pragma unroll
            for (int k = 0; k < 64; ++k) {
                const float4 wa = W14[k * 16 + jb * 2];
                const float4 wb = W14[k * 16 + jb * 2 + 1];
                const float4 va = W24[k * 16 + jb * 2];
                const float4 vb = W24[k * 16 + jb * 2 + 1];
                const float ak = a[k];
                f1[0] += ak * wa.x; f1[1] += ak * wa.y; f1[2] += ak * wa.z; f1[3] += ak * wa.w;
                f1[4] += ak * wb.x; f1[5] += ak * wb.y; f1[6] += ak * wb.z; f1[7] += ak * wb.w;
                f2[0] += ak * va.x; f2[1] += ak * va.y; f2[2] += ak * va.z; f2[3] += ak * va.w;
                f2[4] += ak * vb.x; f2[5] += ak * vb.y; f2[6] += ak * vb.z; f2[7] += ak * vb.w;
            }
            uint4 p;
            p.x = pk_bf16(f1[0], f1[1]); p.y = pk_bf16(f1[2], f1[3]);
            p.z = pk_bf16(f1[4], f1[5]); p.w = pk_bf16(f1[6], f1[7]);
            T1row[jb] = p;
            p.x = pk_bf16(f2[0], f2[1]); p.y = pk_bf16(f2[2], f2[3]);
            p.z = pk_bf16(f2[4], f2[5]); p.w = pk_bf16(f2[6], f2[7]);
            T2row[jb] = p;
        }
    } else {
        // ---------------- fill ----------------
        const int i = (grp * 5 + (r - 2)) * 256 + t;
        const int Q = N_EDGES / 4;
        if (i < Q) {
            int4 sv = src1[i]; int4 dv = dst1[i];
            int p0 = atomicAdd(&ws[WS_CUR1 + dv.x], 1); ws[WS_SORT1 + p0] = sv.x;
            int p1 = atomicAdd(&ws[WS_CUR1 + dv.y], 1); ws[WS_SORT1 + p1] = sv.y;
            int p2 = atomicAdd(&ws[WS_CUR1 + dv.z], 1); ws[WS_SORT1 + p2] = sv.z;
            int p3 = atomicAdd(&ws[WS_CUR1 + dv.w], 1); ws[WS_SORT1 + p3] = sv.w;
        } else if (i < 2 * Q) {
            int e = i - Q;
            int4 sv = src2[e]; int4 dv = dst2[e];
            int p0 = atomicAdd(&ws[WS_CUR2 + dv.x], 1); ws[WS_SORT2 + p0] = sv.x;
            int p1 = atomicAdd(&ws[WS_CUR2 + dv.y], 1); ws[WS_SORT2 + p1] = sv.y;
            int p2 = atomicAdd(&ws[WS_CUR2 + dv.z], 1); ws[WS_SORT2 + p2] = sv.z;
            int p3 = atomicAdd(&ws[WS_CUR2 + dv.w], 1); ws[WS_SORT2 + p3] = sv.w;
        }
    }
}

// Gather-aggregate, one graph per dispatch. 4 waves/block, 8 nodes/wave serial.
// 8 edge-slots x 8 lanes/edge; each lane loads the G-chunk AND S-chunk (2 x 16B).
__global__ __launch_bounds__(256) void k_gather_pre(const int* __restrict__ off,
                                                    const int* __restrict__ sorted,
                                                    const uint4* __restrict__ T,
                                                    const float* __restrict__ bias,
                                                    float* __restrict__ h_f,
                                                    float* __restrict__ h_s,
                                                    float* __restrict__ csum) {
    const int t = threadIdx.x;
    const int wave = t >> 6;
    const int lane = t & 63;
    const int slot = lane >> 3;
    const int sub = lane & 7;

    float bias8[8];
    #pragma unroll
    for (int i = 0; i < 8; ++i) bias8[i] = bias[sub * 8 + i];

    __shared__ float red[4][8][8];
    float csum_acc[8] = {0.f, 0.f, 0.f, 0.f, 0.f, 0.f, 0.f, 0.f};

    const int nb = blockIdx.x * 32 + wave * 8;
    for (int r = 0; r < 8; ++r) {
        const int n = nb + r;
        if (n >= N_NODES) break;
        const int e0 = off[n];
        const int e1 = off[n + 1];

        float ag[8] = {0.f, 0.f, 0.f, 0.f, 0.f, 0.f, 0.f, 0.f};
        float as[8] = {0.f, 0.f, 0.f, 0.f, 0.f, 0.f, 0.f, 0.f};
        int e = e0 + slot;
        for (; e + 8 < e1; e += 16) {
            const int sA = sorted[e];
            const int sB = sorted[e + 8];
            const uint4 gA = T[sA * 16 + sub];
            const uint4 sAv = T[sA * 16 + 8 + sub];
            const uint4 gB = T[sB * 16 + sub];
            const uint4 sBv = T[sB * 16 + 8 + sub];
            ag[0] += bf_lo(gA.x); ag[1] += bf_hi(gA.x);
            ag[2] += bf_lo(gA.y); ag[3] += bf_hi(gA.y);
            ag[4] += bf_lo(gA.z); ag[5] += bf_hi(gA.z);
            ag[6] += bf_lo(gA.w); ag[7] += bf_hi(gA.w);
            as[0] += bf_lo(sAv.x); as[1] += bf_hi(sAv.x);
            as[2] += bf_lo(sAv.y); as[3] += bf_hi(sAv.y);
            as[4] += bf_lo(sAv.z); as[5] += bf_hi(sAv.z);
            as[6] += bf_lo(sAv.w); as[7] += bf_hi(sAv.w);
            ag[0] += bf_lo(gB.x); ag[1] += bf_hi(gB.x);
            ag[2] += bf_lo(gB.y); ag[3] += bf_hi(gB.y);
            ag[4] += bf_lo(gB.z); ag[5] += bf_hi(gB.z);
            ag[6] += bf_lo(gB.w); ag[7] += bf_hi(gB.w);
            as[0] += bf_lo(sBv.x); as[1] += bf_hi(sBv.x);
            as[2] += bf_lo(sBv.y); as[3] += bf_hi(sBv.y);
            as[4] += bf_lo(sBv.z); as[5] += bf_hi(sBv.z);
            as[6] += bf_lo(sBv.w); as[7] += bf_hi(sBv.w);
        }
        if (e < e1) {
            const int s = sorted[e];
            const uint4 gv = T[s * 16 + sub];
            const uint4 sv = T[s * 16 + 8 + sub];
            ag[0] += bf_lo(gv.x); ag[1] += bf_hi(gv.x);
            ag[2] += bf_lo(gv.y); ag[3] += bf_hi(gv.y);
            ag[4] += bf_lo(gv.z); ag[5] += bf_hi(gv.z);
            ag[6] += bf_lo(gv.w); ag[7] += bf_hi(gv.w);
            as[0] += bf_lo(sv.x); as[1] += bf_hi(sv.x);
            as[2] += bf_lo(sv.y); as[3] += bf_hi(sv.y);
            as[4] += bf_lo(sv.z); as[5] += bf_hi(sv.z);
            as[6] += bf_lo(sv.w); as[7] += bf_hi(sv.w);
        }
        #pragma unroll
        for (int i = 0; i < 8; ++i) {
            ag[i] += __shfl_xor(ag[i], 8);
            ag[i] += __shfl_xor(ag[i], 16);
            ag[i] += __shfl_xor(ag[i], 32);
            as[i] += __shfl_xor(as[i], 8);
            as[i] += __shfl_xor(as[i], 16);
            as[i] += __shfl_xor(as[i], 32);
            ag[i] += bias8[i];
            as[i] += bias8[i];
        }
        if (slot == 0) {
            float* p = h_f + (long long)n * DIM + sub * 8;
            f4_t v0 = {ag[0], ag[1], ag[2], ag[3]};
            f4_t v1 = {ag[4], ag[5], ag[6], ag[7]};
            __builtin_nontemporal_store(v0, (f4_t*)p);
            __builtin_nontemporal_store(v1, (f4_t*)(p + 4));
            #pragma unroll
            for (int i = 0; i < 8; ++i) csum_acc[i] += ag[i];
        } else if (slot == 1) {
            float* p = h_s + (long long)n * DIM + sub * 8;
            f4_t v0 = {as[0], as[1], as[2], as[3]};
            f4_t v1 = {as[4], as[5], as[6], as[7]};
            __builtin_nontemporal_store(v0, (f4_t*)p);
            __builtin_nontemporal_store(v1, (f4_t*)(p + 4));
        }
    }

    if (slot == 0) {
        #pragma unroll
        for (int i = 0; i < 8; ++i) red[wave][sub][i] = csum_acc[i];
    }
    __syncthreads();
    if (t < 64) {
        int su = t >> 3, i = t & 7;
        float s4 = red[0][su][i] + red[1][su][i] + red[2][su][i] + red[3][su][i];
        unsafeAtomicAdd(&csum[su * 8 + i], s4);
    }
}

__global__ void k_final(const float* __restrict__ ws_csum, float* __restrict__ out_c) {
    int t = threadIdx.x;  // 0..63 -> c1, 64..127 -> c2
    float m = ws_csum[t] * (1.0f / (float)N_NODES);
    out_c[t] = 1.f / (1.f + expf(-m));
}

extern "C" void kernel_launch(void* const* d_in, const int* in_sizes, int n_in,
                              void* d_out, int out_size, void* d_ws, size_t ws_size,
                              hipStream_t stream) {
    const float* feat = (const float*)d_in[0];
    const float* shuf = (const float*)d_in[1];
    const int* src1 = (const int*)d_in[2];
    const int* dst1 = (const int*)d_in[3];
    const int* src2 = (const int*)d_in[4];
    const int* dst2 = (const int*)d_in[5];
    const float* W1 = (const float*)d_in[6];
    const float* b1 = (const float*)d_in[7];
    const float* W2 = (const float*)d_in[8];
    const float* b2 = (const float*)d_in[9];

    float* out = (float*)d_out;
    int* ws = (int*)d_ws;
    float* ws_f = (float*)d_ws;
    float* c_out = out + 2 * ND;

    k_init<<<(200129 + 255) / 256, 256, 0, stream>>>(ws);
    k_hist<<<(2 * (N_EDGES / 4) + 255) / 256, 256, 0, stream>>>(
        (const int4*)dst1, (const int4*)dst2, ws);
    k_scan1<<<dim3(SCAN_BLOCKS, 2), 256, 0, stream>>>(ws);
    k_scan2<<<1, 256, 0, stream>>>(ws);
    k_scan3<<<dim3(SCAN_BLOCKS, 2), 256, 0, stream>>>(ws);

    k_fill_transform<<<FT_BLOCKS, 256, 0, stream>>>(
        (const int4*)src1, (const int4*)dst1, (const int4*)src2, (const int4*)dst2,
        ws, feat, shuf, W1, W2);

    const int ggrid = (N_NODES + 31) / 32;
    k_gather_pre<<<ggrid, 256, 0, stream>>>(
        ws + WS_OFF1, ws + WS_SORT1, (const uint4*)(ws + WS_T1), b1,
        out, out + 2 * ND + 128, ws_f + WS_CSUM);
    k_gather_pre<<<ggrid, 256, 0, stream>>>(
        ws + WS_OFF2, ws + WS_SORT2, (const uint4*)(ws + WS_T2), b2,
        out + ND, out + 3 * ND + 128, ws_f + WS_CSUM + 64);

    k_final<<<1, 128, 0, stream>>>(ws_f + WS_CSUM, c_out);
}

// Round 9
// 366.537 us; speedup vs baseline: 6.8577x; 1.3062x over previous
//
#include <hip/hip_runtime.h>
#include <hip/hip_bf16.h>

#define N_NODES 100000
#define N_EDGES 1000000
#define DIM 64

static const long long ND = (long long)N_NODES * DIM;  // 6,400,000

typedef float f4_t __attribute__((ext_vector_type(4)));

// d_out layout (floats):
// h1: [0, ND)  h2: [ND, 2*ND)  c1c2: [2*ND, 2*ND+128)  h3: [2*ND+128, ...)  h4: [3*ND+128, ...)

// d_ws layout (4-byte words):
#define WS_OFF1  200000            // 100001 used (region padded)
#define WS_OFF2  300004
#define WS_SORT1 400008            // payload (partition) then sorted src ids (place), 1M
#define WS_SORT2 1400008
#define WS_CSUM  2400008           // 128 floats
#define WS_BSUM  2400136           // 196: bucket counts -> exclusive bases
#define WS_BCUR  2400332           // 196: partition cursors
#define WS_T1    2400640           // bf16 [G|S] rows, 64 words/row, 6.4M words
#define WS_T2    (WS_T1 + 6400000)
#define WS_END   (WS_T2 + 6400000) // 15,200,640 words ~= 58 MB (proven available)

#define NBUCK 98                   // buckets of 1024 nodes; 98*1024 >= 100000
#define PLACE_CAP 13312            // max bucket edges held in LDS (mean 10240, sd ~101)

// fused bucket-hist + transform grid: groups of 9 = 4 transform + 5 hist
#define BT_GROUPS 196              // transform: 196*4=784>=782; hist: 196*5=980>=977
#define BT_BLOCKS (BT_GROUPS * 9)

__device__ __forceinline__ unsigned pk_bf16(float a, float b) {
    __hip_bfloat16 ha = __float2bfloat16(a), hb = __float2bfloat16(b);
    return (unsigned)(*(unsigned short*)&ha) | ((unsigned)(*(unsigned short*)&hb) << 16);
}
__device__ __forceinline__ float bf_lo(unsigned u) { return __uint_as_float(u << 16); }
__device__ __forceinline__ float bf_hi(unsigned u) { return __uint_as_float(u & 0xFFFF0000u); }

__global__ __launch_bounds__(256) void k_init(int* __restrict__ ws) {
    const int t = threadIdx.x;
    if (t < 128) ((float*)ws)[WS_CSUM + t] = 0.f;
    if (t < 196) ws[WS_BSUM + t] = 0;
    if (t == 0) {
        ws[WS_OFF1 + N_NODES] = N_EDGES;
        ws[WS_OFF2 + N_NODES] = N_EDGES;
    }
}

// FUSED bucket-hist + transform. Block role by blockIdx.x % 9: r<4 transform, r>=4 hist.
// Transform: thread per (node, branch), VGPR ~128 (no min-waves in launch_bounds —
// R7's (256,4) capped VGPR at 64 and spilled 7GB/dispatch).
__global__ __launch_bounds__(256) void k_bhist_transform(
    const int4* __restrict__ dst1, const int4* __restrict__ dst2,
    int* __restrict__ ws,
    const float* __restrict__ feat, const float* __restrict__ shuf,
    const float* __restrict__ W1, const float* __restrict__ W2) {
    const int grp = blockIdx.x / 9;
    const int r = blockIdx.x - grp * 9;
    const int t = threadIdx.x;

    if (r < 4) {
        // ---------------- transform ----------------
        __shared__ float Wl[2][64 * 64];
        for (int i = t; i < 64 * 64; i += 256) {
            Wl[0][i] = W1[i];
            Wl[1][i] = W2[i];
        }
        __syncthreads();

        const int gid = (grp * 4 + r) * 256 + t;
        if (gid >= 2 * N_NODES) return;
        const int br = gid >= N_NODES;
        const int n = br ? gid - N_NODES : gid;
        const float* srcp = br ? shuf : feat;

        float a[64];
        const f4_t* a4 = (const f4_t*)(srcp + (long long)n * DIM);
        #pragma unroll
        for (int i = 0; i < 16; ++i) {
            f4_t v = __builtin_nontemporal_load(a4 + i);
            a[4 * i + 0] = v.x; a[4 * i + 1] = v.y;
            a[4 * i + 2] = v.z; a[4 * i + 3] = v.w;
        }

        uint4* T1row = (uint4*)(ws + WS_T1) + (long long)n * 16 + br * 8;
        uint4* T2row = (uint4*)(ws + WS_T2) + (long long)n * 16 + br * 8;
        const float4* W14 = (const float4*)Wl[0];
        const float4* W24 = (const float4*)Wl[1];

        #pragma unroll
        for (int jb = 0; jb < 8; ++jb) {
            float f1[8] = {0,0,0,0,0,0,0,0};
            float f2[8] = {0,0,0,0,0,0,0,0};
            #pragma unroll
            for (int k = 0; k < 64; ++k) {
                const float4 wa = W14[k * 16 + jb * 2];
                const float4 wb = W14[k * 16 + jb * 2 + 1];
                const float4 va = W24[k * 16 + jb * 2];
                const float4 vb = W24[k * 16 + jb * 2 + 1];
                const float ak = a[k];
                f1[0] += ak * wa.x; f1[1] += ak * wa.y; f1[2] += ak * wa.z; f1[3] += ak * wa.w;
                f1[4] += ak * wb.x; f1[5] += ak * wb.y; f1[6] += ak * wb.z; f1[7] += ak * wb.w;
                f2[0] += ak * va.x; f2[1] += ak * va.y; f2[2] += ak * va.z; f2[3] += ak * va.w;
                f2[4] += ak * vb.x; f2[5] += ak * vb.y; f2[6] += ak * vb.z; f2[7] += ak * vb.w;
            }
            uint4 p;
            p.x = pk_bf16(f1[0], f1[1]); p.y = pk_bf16(f1[2], f1[3]);
            p.z = pk_bf16(f1[4], f1[5]); p.w = pk_bf16(f1[6], f1[7]);
            T1row[jb] = p;
            p.x = pk_bf16(f2[0], f2[1]); p.y = pk_bf16(f2[2], f2[3]);
            p.z = pk_bf16(f2[4], f2[5]); p.w = pk_bf16(f2[6], f2[7]);
            T2row[jb] = p;
        }
    } else {
        // ---------------- bucket hist (LDS-privatized) ----------------
        __shared__ int lcnt[2 * NBUCK];
        for (int i = t; i < 2 * NBUCK; i += 256) lcnt[i] = 0;
        __syncthreads();
        const int Q = N_EDGES / 4;
        const int qb = (grp * 5 + (r - 4)) * 512;
        #pragma unroll
        for (int k = 0; k < 2; ++k) {
            const int q = qb + k * 256 + t;
            if (q < 2 * Q) {
                const int4 d = (q < Q) ? dst1[q] : dst2[q - Q];
                const int gb = (q < Q) ? 0 : NBUCK;
                atomicAdd(&lcnt[gb + (d.x >> 10)], 1);
                atomicAdd(&lcnt[gb + (d.y >> 10)], 1);
                atomicAdd(&lcnt[gb + (d.z >> 10)], 1);
                atomicAdd(&lcnt[gb + (d.w >> 10)], 1);
            }
        }
        __syncthreads();
        if (t < 2 * NBUCK && lcnt[t] != 0) atomicAdd(&ws[WS_BSUM + t], lcnt[t]);
    }
}

// Segmented exclusive scan of the 2x98 bucket counts (in place) + copy to cursors.
__global__ __launch_bounds__(256) void k_bscan(int* __restrict__ ws) {
    const int t = threadIdx.x;
    const int n = 2 * NBUCK;
    __shared__ int s[256];
    s[t] = (t < n) ? ws[WS_BSUM + t] : 0;
    __syncthreads();
    for (int d = 1; d < 256; d <<= 1) {
        int v = 0;
        if (t >= d && (t < NBUCK || t - d >= NBUCK)) v = s[t - d];
        __syncthreads();
        s[t] += v;
        __syncthreads();
    }
    if (t < n) {
        const int excl = (t == 0 || t == NBUCK) ? 0 : s[t - 1];
        ws[WS_BSUM + t] = excl;
        ws[WS_BCUR + t] = excl;
    }
}

// Partition: scatter packed payloads (src | dstlocal<<17) into SORT grouped by
// bucket, via block-level range reservation (dense per-block runs -> L2-friendly).
__global__ __launch_bounds__(256) void k_partition(
    const int4* __restrict__ src1, const int4* __restrict__ dst1,
    const int4* __restrict__ src2, const int4* __restrict__ dst2,
    int* __restrict__ ws) {
    const int g = blockIdx.y;
    const int t = threadIdx.x;
    __shared__ int lcnt[NBUCK];
    __shared__ int lbase[NBUCK];
    const int4* sv4 = g ? src2 : src1;
    const int4* dv4 = g ? dst2 : dst1;
    int* sortp = ws + (g ? WS_SORT2 : WS_SORT1);
    int* bcur = ws + WS_BCUR + g * NBUCK;
    const int Q = N_EDGES / 4;

    const int q0 = blockIdx.x * 512 + t;
    const int q1 = q0 + 256;
    const bool v0 = q0 < Q, v1 = q1 < Q;
    int4 s0, d0, s1, d1;
    if (v0) { s0 = sv4[q0]; d0 = dv4[q0]; }
    if (v1) { s1 = sv4[q1]; d1 = dv4[q1]; }

    for (int i = t; i < NBUCK; i += 256) lcnt[i] = 0;
    __syncthreads();
    if (v0) {
        atomicAdd(&lcnt[d0.x >> 10], 1); atomicAdd(&lcnt[d0.y >> 10], 1);
        atomicAdd(&lcnt[d0.z >> 10], 1); atomicAdd(&lcnt[d0.w >> 10], 1);
    }
    if (v1) {
        atomicAdd(&lcnt[d1.x >> 10], 1); atomicAdd(&lcnt[d1.y >> 10], 1);
        atomicAdd(&lcnt[d1.z >> 10], 1); atomicAdd(&lcnt[d1.w >> 10], 1);
    }
    __syncthreads();
    if (t < NBUCK) lbase[t] = lcnt[t] ? atomicAdd(&bcur[t], lcnt[t]) : 0;
    __syncthreads();

#define PUT(ss, dd) { const int b_ = (dd) >> 10; \
    const int pos_ = atomicAdd(&lbase[b_], 1); \
    sortp[pos_] = (ss) | (((dd) & 1023) << 17); }
    if (v0) { PUT(s0.x, d0.x); PUT(s0.y, d0.y); PUT(s0.z, d0.z); PUT(s0.w, d0.w); }
    if (v1) { PUT(s1.x, d1.x); PUT(s1.y, d1.y); PUT(s1.z, d1.z); PUT(s1.w, d1.w); }
#undef PUT
}

// Place: one block per (bucket, graph). Load bucket payloads fully into LDS,
// local per-node hist + exclusive scan -> off[], then in-place scatter of src
// ids within the bucket's contiguous (L2-resident) window.
__global__ __launch_bounds__(256) void k_place(int* __restrict__ ws) {
    const int g = blockIdx.y;
    const int b = blockIdx.x;
    const int t = threadIdx.x;
    __shared__ int pl[PLACE_CAP];
    __shared__ int lcur[1024];
    __shared__ int sscan[256];

    const int base = ws[WS_BSUM + g * NBUCK + b];
    const int end = (b == NBUCK - 1) ? N_EDGES : ws[WS_BSUM + g * NBUCK + b + 1];
    int cnt = end - base;
    if (cnt > PLACE_CAP) cnt = PLACE_CAP;   // safety clamp (30-sigma margin, never hit)
    int* sortp = ws + (g ? WS_SORT2 : WS_SORT1);
    int* off = ws + (g ? WS_OFF2 : WS_OFF1);
    const int node0 = b << 10;

    for (int i = t; i < cnt; i += 256) pl[i] = sortp[base + i];
    for (int i = t; i < 1024; i += 256) lcur[i] = 0;
    __syncthreads();
    for (int i = t; i < cnt; i += 256) atomicAdd(&lcur[(pl[i] >> 17) & 1023], 1);
    __syncthreads();

    // exclusive scan of lcur[1024]: per-thread 4-chunk + block scan
    const int c0 = lcur[4 * t], c1 = lcur[4 * t + 1], c2 = lcur[4 * t + 2], c3 = lcur[4 * t + 3];
    sscan[t] = c0 + c1 + c2 + c3;
    __syncthreads();
    for (int d = 1; d < 256; d <<= 1) {
        int v = 0;
        if (t >= d) v = sscan[t - d];
        __syncthreads();
        sscan[t] += v;
        __syncthreads();
    }
    const int excl = (t == 0) ? 0 : sscan[t - 1];
    const int p0 = base + excl, p1 = p0 + c0, p2 = p1 + c1, p3 = p2 + c2;
    lcur[4 * t] = p0; lcur[4 * t + 1] = p1; lcur[4 * t + 2] = p2; lcur[4 * t + 3] = p3;
    // write off[] (global CSR row offsets), guarded at the tail bucket
    const int idx = node0 + 4 * t;
    if (idx + 3 < N_NODES) {
        *(int4*)(off + idx) = make_int4(p0, p1, p2, p3);
    } else {
        if (idx + 0 < N_NODES) off[idx + 0] = p0;
        if (idx + 1 < N_NODES) off[idx + 1] = p1;
        if (idx + 2 < N_NODES) off[idx + 2] = p2;
        if (idx + 3 < N_NODES) off[idx + 3] = p3;
    }
    __syncthreads();
    for (int i = t; i < cnt; i += 256) {
        const int p = pl[i];
        const int pos = atomicAdd(&lcur[(p >> 17) & 1023], 1);
        sortp[pos] = p & 0x1FFFF;
    }
}

// Gather-aggregate, both graphs in one dispatch (blockIdx.y = graph).
// 4 waves/block, 8 nodes/wave serial; 8 edge-slots x 8 lanes; lane loads the
// G-chunk AND S-chunk (2 x 16B) of its slot's row; unroll-2 -> 16 rows in flight.
__global__ __launch_bounds__(256) void k_gather_pre(int* __restrict__ ws,
                                                    const float* __restrict__ b1,
                                                    const float* __restrict__ b2,
                                                    float* __restrict__ out) {
    const int g = blockIdx.y;
    const int* off    = ws + (g ? WS_OFF2 : WS_OFF1);
    const int* sorted = ws + (g ? WS_SORT2 : WS_SORT1);
    const uint4* T = (const uint4*)(ws + (g ? WS_T2 : WS_T1));
    const float* bias = g ? b2 : b1;
    float* h_f = out + (g ? ND : 0);
    float* h_s = out + (g ? 3 * ND + 128 : 2 * ND + 128);
    float* csum = (float*)ws + WS_CSUM + g * 64;

    const int t = threadIdx.x;
    const int wave = t >> 6;
    const int lane = t & 63;
    const int slot = lane >> 3;
    const int sub = lane & 7;

    float bias8[8];
    #pragma unroll
    for (int i = 0; i < 8; ++i) bias8[i] = bias[sub * 8 + i];

    __shared__ float red[4][8][8];
    float csum_acc[8] = {0.f, 0.f, 0.f, 0.f, 0.f, 0.f, 0.f, 0.f};

    const int nb = blockIdx.x * 32 + wave * 8;
    for (int r = 0; r < 8; ++r) {
        const int n = nb + r;
        if (n >= N_NODES) break;
        const int e0 = off[n];
        const int e1 = off[n + 1];

        float ag[8] = {0.f, 0.f, 0.f, 0.f, 0.f, 0.f, 0.f, 0.f};
        float as[8] = {0.f, 0.f, 0.f, 0.f, 0.f, 0.f, 0.f, 0.f};
        int e = e0 + slot;
        for (; e + 8 < e1; e += 16) {
            const int sA = sorted[e];
            const int sB = sorted[e + 8];
            const uint4 gA = T[sA * 16 + sub];
            const uint4 sAv = T[sA * 16 + 8 + sub];
            const uint4 gB = T[sB * 16 + sub];
            const uint4 sBv = T[sB * 16 + 8 + sub];
            ag[0] += bf_lo(gA.x); ag[1] += bf_hi(gA.x);
            ag[2] += bf_lo(gA.y); ag[3] += bf_hi(gA.y);
            ag[4] += bf_lo(gA.z); ag[5] += bf_hi(gA.z);
            ag[6] += bf_lo(gA.w); ag[7] += bf_hi(gA.w);
            as[0] += bf_lo(sAv.x); as[1] += bf_hi(sAv.x);
            as[2] += bf_lo(sAv.y); as[3] += bf_hi(sAv.y);
            as[4] += bf_lo(sAv.z); as[5] += bf_hi(sAv.z);
            as[6] += bf_lo(sAv.w); as[7] += bf_hi(sAv.w);
            ag[0] += bf_lo(gB.x); ag[1] += bf_hi(gB.x);
            ag[2] += bf_lo(gB.y); ag[3] += bf_hi(gB.y);
            ag[4] += bf_lo(gB.z); ag[5] += bf_hi(gB.z);
            ag[6] += bf_lo(gB.w); ag[7] += bf_hi(gB.w);
            as[0] += bf_lo(sBv.x); as[1] += bf_hi(sBv.x);
            as[2] += bf_lo(sBv.y); as[3] += bf_hi(sBv.y);
            as[4] += bf_lo(sBv.z); as[5] += bf_hi(sBv.z);
            as[6] += bf_lo(sBv.w); as[7] += bf_hi(sBv.w);
        }
        if (e < e1) {
            const int s = sorted[e];
            const uint4 gv = T[s * 16 + sub];
            const uint4 sv = T[s * 16 + 8 + sub];
            ag[0] += bf_lo(gv.x); ag[1] += bf_hi(gv.x);
            ag[2] += bf_lo(gv.y); ag[3] += bf_hi(gv.y);
            ag[4] += bf_lo(gv.z); ag[5] += bf_hi(gv.z);
            ag[6] += bf_lo(gv.w); ag[7] += bf_hi(gv.w);
            as[0] += bf_lo(sv.x); as[1] += bf_hi(sv.x);
            as[2] += bf_lo(sv.y); as[3] += bf_hi(sv.y);
            as[4] += bf_lo(sv.z); as[5] += bf_hi(sv.z);
            as[6] += bf_lo(sv.w); as[7] += bf_hi(sv.w);
        }
        #pragma unroll
        for (int i = 0; i < 8; ++i) {
            ag[i] += __shfl_xor(ag[i], 8);
            ag[i] += __shfl_xor(ag[i], 16);
            ag[i] += __shfl_xor(ag[i], 32);
            as[i] += __shfl_xor(as[i], 8);
            as[i] += __shfl_xor(as[i], 16);
            as[i] += __shfl_xor(as[i], 32);
            ag[i] += bias8[i];
            as[i] += bias8[i];
        }
        if (slot == 0) {
            float* p = h_f + (long long)n * DIM + sub * 8;
            f4_t v0 = {ag[0], ag[1], ag[2], ag[3]};
            f4_t v1 = {ag[4], ag[5], ag[6], ag[7]};
            __builtin_nontemporal_store(v0, (f4_t*)p);
            __builtin_nontemporal_store(v1, (f4_t*)(p + 4));
            #pragma unroll
            for (int i = 0; i < 8; ++i) csum_acc[i] += ag[i];
        } else if (slot == 1) {
            float* p = h_s + (long long)n * DIM + sub * 8;
            f4_t v0 = {as[0], as[1], as[2], as[3]};
            f4_t v1 = {as[4], as[5], as[6], as[7]};
            __builtin_nontemporal_store(v0, (f4_t*)p);
            __builtin_nontemporal_store(v1, (f4_t*)(p + 4));
        }
    }

    if (slot == 0) {
        #pragma unroll
        for (int i = 0; i < 8; ++i) red[wave][sub][i] = csum_acc[i];
    }
    __syncthreads();
    if (t < 64) {
        int su = t >> 3, i = t & 7;
        float s4 = red[0][su][i] + red[1][su][i] + red[2][su][i] + red[3][su][i];
        unsafeAtomicAdd(&csum[su * 8 + i], s4);
    }
}

__global__ void k_final(const float* __restrict__ ws_csum, float* __restrict__ out_c) {
    int t = threadIdx.x;  // 0..63 -> c1, 64..127 -> c2
    float m = ws_csum[t] * (1.0f / (float)N_NODES);
    out_c[t] = 1.f / (1.f + expf(-m));
}

extern "C" void kernel_launch(void* const* d_in, const int* in_sizes, int n_in,
                              void* d_out, int out_size, void* d_ws, size_t ws_size,
                              hipStream_t stream) {
    const float* feat = (const float*)d_in[0];
    const float* shuf = (const float*)d_in[1];
    const int* src1 = (const int*)d_in[2];
    const int* dst1 = (const int*)d_in[3];
    const int* src2 = (const int*)d_in[4];
    const int* dst2 = (const int*)d_in[5];
    const float* W1 = (const float*)d_in[6];
    const float* b1 = (const float*)d_in[7];
    const float* W2 = (const float*)d_in[8];
    const float* b2 = (const float*)d_in[9];

    float* out = (float*)d_out;
    int* ws = (int*)d_ws;
    float* ws_f = (float*)d_ws;
    float* c_out = out + 2 * ND;

    k_init<<<1, 256, 0, stream>>>(ws);
    k_bhist_transform<<<BT_BLOCKS, 256, 0, stream>>>(
        (const int4*)dst1, (const int4*)dst2, ws, feat, shuf, W1, W2);
    k_bscan<<<1, 256, 0, stream>>>(ws);
    k_partition<<<dim3((N_EDGES / 4 + 511) / 512, 2), 256, 0, stream>>>(
        (const int4*)src1, (const int4*)dst1, (const int4*)src2, (const int4*)dst2, ws);
    k_place<<<dim3(NBUCK, 2), 256, 0, stream>>>(ws);
    k_gather_pre<<<dim3((N_NODES + 31) / 32, 2), 256, 0, stream>>>(ws, b1, b2, out);
    k_final<<<1, 128, 0, stream>>>(ws_f + WS_CSUM, c_out);
}

// Round 10
// 350.769 us; speedup vs baseline: 7.1659x; 1.0450x over previous
//
#include <hip/hip_runtime.h>
#include <hip/hip_bf16.h>

#define N_NODES 100000
#define N_EDGES 1000000
#define DIM 64

static const long long ND = (long long)N_NODES * DIM;  // 6,400,000

typedef float f4_t __attribute__((ext_vector_type(4)));

// d_out layout (floats):
// h1: [0, ND)  h2: [ND, 2*ND)  c1c2: [2*ND, 2*ND+128)  h3: [2*ND+128, ...)  h4: [3*ND+128, ...)

// d_ws layout (4-byte words):
#define WS_OFF1  200000            // 100001 used (region padded)
#define WS_OFF2  300004
#define WS_SORT1 400008            // payload (partition) then sorted src ids (place), 1M
#define WS_SORT2 1400008
#define WS_CSUM  2400008           // 128 floats
#define WS_BSUM  2400136           // 196: bucket counts -> exclusive bases
#define WS_BCUR  2400332           // 196: partition cursors
#define WS_T1    2400640           // bf16 [G|S] rows, 64 words/row, 6.4M words
#define WS_T2    (WS_T1 + 6400000)
#define WS_END   (WS_T2 + 6400000) // 15,200,640 words ~= 58 MB (proven available)

#define NBUCK 98                   // buckets of 1024 nodes; 98*1024 >= 100000
#define PLACE_CAP 13312            // max bucket edges held in LDS (mean 10240, sd ~101)

// fused bucket-hist + transform grid: groups of 9 = 4 transform + 5 hist
#define BT_GROUPS 196              // transform: 196*4=784>=782; hist: 196*5=980>=977
#define BT_BLOCKS (BT_GROUPS * 9)

__device__ __forceinline__ unsigned pk_bf16(float a, float b) {
    __hip_bfloat16 ha = __float2bfloat16(a), hb = __float2bfloat16(b);
    return (unsigned)(*(unsigned short*)&ha) | ((unsigned)(*(unsigned short*)&hb) << 16);
}
__device__ __forceinline__ float bf_lo(unsigned u) { return __uint_as_float(u << 16); }
__device__ __forceinline__ float bf_hi(unsigned u) { return __uint_as_float(u & 0xFFFF0000u); }

__global__ __launch_bounds__(256) void k_init(int* __restrict__ ws) {
    const int t = threadIdx.x;
    if (t < 128) ((float*)ws)[WS_CSUM + t] = 0.f;
    if (t < 196) ws[WS_BSUM + t] = 0;
    if (t == 0) {
        ws[WS_OFF1 + N_NODES] = N_EDGES;
        ws[WS_OFF2 + N_NODES] = N_EDGES;
    }
}

// FUSED bucket-hist + transform. Block role by blockIdx.x % 9: r<4 transform, r>=4 hist.
// Transform: thread per (node, branch), VGPR ~128 (no min-waves in launch_bounds —
// R7's (256,4) capped VGPR at 64 and spilled 7GB/dispatch).
__global__ __launch_bounds__(256) void k_bhist_transform(
    const int4* __restrict__ dst1, const int4* __restrict__ dst2,
    int* __restrict__ ws,
    const float* __restrict__ feat, const float* __restrict__ shuf,
    const float* __restrict__ W1, const float* __restrict__ W2) {
    const int grp = blockIdx.x / 9;
    const int r = blockIdx.x - grp * 9;
    const int t = threadIdx.x;

    if (r < 4) {
        // ---------------- transform ----------------
        __shared__ float Wl[2][64 * 64];
        for (int i = t; i < 64 * 64; i += 256) {
            Wl[0][i] = W1[i];
            Wl[1][i] = W2[i];
        }
        __syncthreads();

        const int gid = (grp * 4 + r) * 256 + t;
        if (gid >= 2 * N_NODES) return;
        const int br = gid >= N_NODES;
        const int n = br ? gid - N_NODES : gid;
        const float* srcp = br ? shuf : feat;

        float a[64];
        const f4_t* a4 = (const f4_t*)(srcp + (long long)n * DIM);
        #pragma unroll
        for (int i = 0; i < 16; ++i) {
            f4_t v = __builtin_nontemporal_load(a4 + i);
            a[4 * i + 0] = v.x; a[4 * i + 1] = v.y;
            a[4 * i + 2] = v.z; a[4 * i + 3] = v.w;
        }

        uint4* T1row = (uint4*)(ws + WS_T1) + (long long)n * 16 + br * 8;
        uint4* T2row = (uint4*)(ws + WS_T2) + (long long)n * 16 + br * 8;
        const float4* W14 = (const float4*)Wl[0];
        const float4* W24 = (const float4*)Wl[1];

        #pragma unroll
        for (int jb = 0; jb < 8; ++jb) {
            float f1[8] = {0,0,0,0,0,0,0,0};
            float f2[8] = {0,0,0,0,0,0,0,0};
            #pragma unroll
            for (int k = 0; k < 64; ++k) {
                const float4 wa = W14[k * 16 + jb * 2];
                const float4 wb = W14[k * 16 + jb * 2 + 1];
                const float4 va = W24[k * 16 + jb * 2];
                const float4 vb = W24[k * 16 + jb * 2 + 1];
                const float ak = a[k];
                f1[0] += ak * wa.x; f1[1] += ak * wa.y; f1[2] += ak * wa.z; f1[3] += ak * wa.w;
                f1[4] += ak * wb.x; f1[5] += ak * wb.y; f1[6] += ak * wb.z; f1[7] += ak * wb.w;
                f2[0] += ak * va.x; f2[1] += ak * va.y; f2[2] += ak * va.z; f2[3] += ak * va.w;
                f2[4] += ak * vb.x; f2[5] += ak * vb.y; f2[6] += ak * vb.z; f2[7] += ak * vb.w;
            }
            uint4 p;
            p.x = pk_bf16(f1[0], f1[1]); p.y = pk_bf16(f1[2], f1[3]);
            p.z = pk_bf16(f1[4], f1[5]); p.w = pk_bf16(f1[6], f1[7]);
            T1row[jb] = p;
            p.x = pk_bf16(f2[0], f2[1]); p.y = pk_bf16(f2[2], f2[3]);
            p.z = pk_bf16(f2[4], f2[5]); p.w = pk_bf16(f2[6], f2[7]);
            T2row[jb] = p;
        }
    } else {
        // ---------------- bucket hist (LDS-privatized) ----------------
        __shared__ int lcnt[2 * NBUCK];
        for (int i = t; i < 2 * NBUCK; i += 256) lcnt[i] = 0;
        __syncthreads();
        const int Q = N_EDGES / 4;
        const int qb = (grp * 5 + (r - 4)) * 512;
        #pragma unroll
        for (int k = 0; k < 2; ++k) {
            const int q = qb + k * 256 + t;
            if (q < 2 * Q) {
                const int4 d = (q < Q) ? dst1[q] : dst2[q - Q];
                const int gb = (q < Q) ? 0 : NBUCK;
                atomicAdd(&lcnt[gb + (d.x >> 10)], 1);
                atomicAdd(&lcnt[gb + (d.y >> 10)], 1);
                atomicAdd(&lcnt[gb + (d.z >> 10)], 1);
                atomicAdd(&lcnt[gb + (d.w >> 10)], 1);
            }
        }
        __syncthreads();
        if (t < 2 * NBUCK && lcnt[t] != 0) atomicAdd(&ws[WS_BSUM + t], lcnt[t]);
    }
}

// Segmented exclusive scan of the 2x98 bucket counts (in place) + copy to cursors.
__global__ __launch_bounds__(256) void k_bscan(int* __restrict__ ws) {
    const int t = threadIdx.x;
    const int n = 2 * NBUCK;
    __shared__ int s[256];
    s[t] = (t < n) ? ws[WS_BSUM + t] : 0;
    __syncthreads();
    for (int d = 1; d < 256; d <<= 1) {
        int v = 0;
        if (t >= d && (t < NBUCK || t - d >= NBUCK)) v = s[t - d];
        __syncthreads();
        s[t] += v;
        __syncthreads();
    }
    if (t < n) {
        const int excl = (t == 0 || t == NBUCK) ? 0 : s[t - 1];
        ws[WS_BSUM + t] = excl;
        ws[WS_BCUR + t] = excl;
    }
}

// Partition: scatter packed payloads (src | dstlocal<<17) into SORT grouped by
// bucket, via block-level range reservation (dense per-block runs -> L2-friendly).
__global__ __launch_bounds__(256) void k_partition(
    const int4* __restrict__ src1, const int4* __restrict__ dst1,
    const int4* __restrict__ src2, const int4* __restrict__ dst2,
    int* __restrict__ ws) {
    const int g = blockIdx.y;
    const int t = threadIdx.x;
    __shared__ int lcnt[NBUCK];
    __shared__ int lbase[NBUCK];
    const int4* sv4 = g ? src2 : src1;
    const int4* dv4 = g ? dst2 : dst1;
    int* sortp = ws + (g ? WS_SORT2 : WS_SORT1);
    int* bcur = ws + WS_BCUR + g * NBUCK;
    const int Q = N_EDGES / 4;

    const int q0 = blockIdx.x * 512 + t;
    const int q1 = q0 + 256;
    const bool v0 = q0 < Q, v1 = q1 < Q;
    int4 s0, d0, s1, d1;
    if (v0) { s0 = sv4[q0]; d0 = dv4[q0]; }
    if (v1) { s1 = sv4[q1]; d1 = dv4[q1]; }

    for (int i = t; i < NBUCK; i += 256) lcnt[i] = 0;
    __syncthreads();
    if (v0) {
        atomicAdd(&lcnt[d0.x >> 10], 1); atomicAdd(&lcnt[d0.y >> 10], 1);
        atomicAdd(&lcnt[d0.z >> 10], 1); atomicAdd(&lcnt[d0.w >> 10], 1);
    }
    if (v1) {
        atomicAdd(&lcnt[d1.x >> 10], 1); atomicAdd(&lcnt[d1.y >> 10], 1);
        atomicAdd(&lcnt[d1.z >> 10], 1); atomicAdd(&lcnt[d1.w >> 10], 1);
    }
    __syncthreads();
    if (t < NBUCK) lbase[t] = lcnt[t] ? atomicAdd(&bcur[t], lcnt[t]) : 0;
    __syncthreads();

#define PUT(ss, dd) { const int b_ = (dd) >> 10; \
    const int pos_ = atomicAdd(&lbase[b_], 1); \
    sortp[pos_] = (ss) | (((dd) & 1023) << 17); }
    if (v0) { PUT(s0.x, d0.x); PUT(s0.y, d0.y); PUT(s0.z, d0.z); PUT(s0.w, d0.w); }
    if (v1) { PUT(s1.x, d1.x); PUT(s1.y, d1.y); PUT(s1.z, d1.z); PUT(s1.w, d1.w); }
#undef PUT
}

// Place: one block per (bucket, graph). Load bucket payloads fully into LDS,
// local per-node hist + exclusive scan -> off[], then in-place scatter of src
// ids within the bucket's contiguous (L2-resident) window.
__global__ __launch_bounds__(256) void k_place(int* __restrict__ ws) {
    const int g = blockIdx.y;
    const int b = blockIdx.x;
    const int t = threadIdx.x;
    __shared__ int pl[PLACE_CAP];
    __shared__ int lcur[1024];
    __shared__ int sscan[256];

    const int base = ws[WS_BSUM + g * NBUCK + b];
    const int end = (b == NBUCK - 1) ? N_EDGES : ws[WS_BSUM + g * NBUCK + b + 1];
    int cnt = end - base;
    if (cnt > PLACE_CAP) cnt = PLACE_CAP;   // safety clamp (30-sigma margin, never hit)
    int* sortp = ws + (g ? WS_SORT2 : WS_SORT1);
    int* off = ws + (g ? WS_OFF2 : WS_OFF1);
    const int node0 = b << 10;

    for (int i = t; i < cnt; i += 256) pl[i] = sortp[base + i];
    for (int i = t; i < 1024; i += 256) lcur[i] = 0;
    __syncthreads();
    for (int i = t; i < cnt; i += 256) atomicAdd(&lcur[(pl[i] >> 17) & 1023], 1);
    __syncthreads();

    // exclusive scan of lcur[1024]: per-thread 4-chunk + block scan
    const int c0 = lcur[4 * t], c1 = lcur[4 * t + 1], c2 = lcur[4 * t + 2], c3 = lcur[4 * t + 3];
    sscan[t] = c0 + c1 + c2 + c3;
    __syncthreads();
    for (int d = 1; d < 256; d <<= 1) {
        int v = 0;
        if (t >= d) v = sscan[t - d];
        __syncthreads();
        sscan[t] += v;
        __syncthreads();
    }
    const int excl = (t == 0) ? 0 : sscan[t - 1];
    const int p0 = base + excl, p1 = p0 + c0, p2 = p1 + c1, p3 = p2 + c2;
    lcur[4 * t] = p0; lcur[4 * t + 1] = p1; lcur[4 * t + 2] = p2; lcur[4 * t + 3] = p3;
    // write off[] (global CSR row offsets), guarded at the tail bucket
    const int idx = node0 + 4 * t;
    if (idx + 3 < N_NODES) {
        *(int4*)(off + idx) = make_int4(p0, p1, p2, p3);
    } else {
        if (idx + 0 < N_NODES) off[idx + 0] = p0;
        if (idx + 1 < N_NODES) off[idx + 1] = p1;
        if (idx + 2 < N_NODES) off[idx + 2] = p2;
        if (idx + 3 < N_NODES) off[idx + 3] = p3;
    }
    __syncthreads();
    for (int i = t; i < cnt; i += 256) {
        const int p = pl[i];
        const int pos = atomicAdd(&lcur[(p >> 17) & 1023], 1);
        sortp[pos] = p & 0x1FFFF;
    }
}

// Gather-aggregate, both graphs (blockIdx.y = graph). ONE NODE PER 8-LANE GROUP:
// 8 nodes concurrently per wave, 32 per block. Lane sub owns dims [8sub,8sub+8)
// of BOTH G and S halves -> no cross-lane reduce; bias+store directly.
// Per edge: lane loads G-chunk + S-chunk (2 x 16B); 8-lane group covers 256B row.
__global__ __launch_bounds__(256) void k_gather_pre(int* __restrict__ ws,
                                                    const float* __restrict__ b1,
                                                    const float* __restrict__ b2,
                                                    float* __restrict__ out) {
    const int g = blockIdx.y;
    const int* off    = ws + (g ? WS_OFF2 : WS_OFF1);
    const int* sorted = ws + (g ? WS_SORT2 : WS_SORT1);
    const uint4* T = (const uint4*)(ws + (g ? WS_T2 : WS_T1));
    const float* bias = g ? b2 : b1;
    float* h_f = out + (g ? ND : 0);
    float* h_s = out + (g ? 3 * ND + 128 : 2 * ND + 128);
    float* csum = (float*)ws + WS_CSUM + g * 64;

    const int t = threadIdx.x;
    const int wave = t >> 6;
    const int lane = t & 63;
    const int nslot = lane >> 3;   // which node of the wave's 8
    const int sub = lane & 7;      // dim chunk within the row

    float bias8[8];
    #pragma unroll
    for (int i = 0; i < 8; ++i) bias8[i] = bias[sub * 8 + i];

    float ag[8] = {0.f, 0.f, 0.f, 0.f, 0.f, 0.f, 0.f, 0.f};
    float as[8] = {0.f, 0.f, 0.f, 0.f, 0.f, 0.f, 0.f, 0.f};

    const int n = blockIdx.x * 32 + wave * 8 + nslot;
    if (n < N_NODES) {
        const int e0 = off[n];
        const int e1 = off[n + 1];
        int e = e0;
        for (; e + 1 < e1; e += 2) {
            const int sA = sorted[e];
            const int sB = sorted[e + 1];
            const uint4 gA = T[sA * 16 + sub];
            const uint4 sAv = T[sA * 16 + 8 + sub];
            const uint4 gB = T[sB * 16 + sub];
            const uint4 sBv = T[sB * 16 + 8 + sub];
            ag[0] += bf_lo(gA.x); ag[1] += bf_hi(gA.x);
            ag[2] += bf_lo(gA.y); ag[3] += bf_hi(gA.y);
            ag[4] += bf_lo(gA.z); ag[5] += bf_hi(gA.z);
            ag[6] += bf_lo(gA.w); ag[7] += bf_hi(gA.w);
            as[0] += bf_lo(sAv.x); as[1] += bf_hi(sAv.x);
            as[2] += bf_lo(sAv.y); as[3] += bf_hi(sAv.y);
            as[4] += bf_lo(sAv.z); as[5] += bf_hi(sAv.z);
            as[6] += bf_lo(sAv.w); as[7] += bf_hi(sAv.w);
            ag[0] += bf_lo(gB.x); ag[1] += bf_hi(gB.x);
            ag[2] += bf_lo(gB.y); ag[3] += bf_hi(gB.y);
            ag[4] += bf_lo(gB.z); ag[5] += bf_hi(gB.z);
            ag[6] += bf_lo(gB.w); ag[7] += bf_hi(gB.w);
            as[0] += bf_lo(sBv.x); as[1] += bf_hi(sBv.x);
            as[2] += bf_lo(sBv.y); as[3] += bf_hi(sBv.y);
            as[4] += bf_lo(sBv.z); as[5] += bf_hi(sBv.z);
            as[6] += bf_lo(sBv.w); as[7] += bf_hi(sBv.w);
        }
        if (e < e1) {
            const int s = sorted[e];
            const uint4 gv = T[s * 16 + sub];
            const uint4 sv = T[s * 16 + 8 + sub];
            ag[0] += bf_lo(gv.x); ag[1] += bf_hi(gv.x);
            ag[2] += bf_lo(gv.y); ag[3] += bf_hi(gv.y);
            ag[4] += bf_lo(gv.z); ag[5] += bf_hi(gv.z);
            ag[6] += bf_lo(gv.w); ag[7] += bf_hi(gv.w);
            as[0] += bf_lo(sv.x); as[1] += bf_hi(sv.x);
            as[2] += bf_lo(sv.y); as[3] += bf_hi(sv.y);
            as[4] += bf_lo(sv.z); as[5] += bf_hi(sv.z);
            as[6] += bf_lo(sv.w); as[7] += bf_hi(sv.w);
        }
        #pragma unroll
        for (int i = 0; i < 8; ++i) {
            ag[i] += bias8[i];
            as[i] += bias8[i];
        }
        float* pf = h_f + (long long)n * DIM + sub * 8;
        f4_t v0 = {ag[0], ag[1], ag[2], ag[3]};
        f4_t v1 = {ag[4], ag[5], ag[6], ag[7]};
        __builtin_nontemporal_store(v0, (f4_t*)pf);
        __builtin_nontemporal_store(v1, (f4_t*)(pf + 4));
        float* ps = h_s + (long long)n * DIM + sub * 8;
        f4_t u0 = {as[0], as[1], as[2], as[3]};
        f4_t u1 = {as[4], as[5], as[6], as[7]};
        __builtin_nontemporal_store(u0, (f4_t*)ps);
        __builtin_nontemporal_store(u1, (f4_t*)(ps + 4));
    } else {
        #pragma unroll
        for (int i = 0; i < 8; ++i) ag[i] = 0.f;   // no bias for nonexistent node
    }

    // csum (feat branch): sum ag across the wave's 8 node-slots (lane bits 3,4,5)
    __shared__ float red[4][8][8];
    #pragma unroll
    for (int i = 0; i < 8; ++i) {
        float v = ag[i];
        v += __shfl_xor(v, 8);
        v += __shfl_xor(v, 16);
        v += __shfl_xor(v, 32);
        if (lane < 8) red[wave][sub][i] = v;
    }
    __syncthreads();
    if (t < 64) {
        const int su = t >> 3, i = t & 7;
        const float s4 = red[0][su][i] + red[1][su][i] + red[2][su][i] + red[3][su][i];
        unsafeAtomicAdd(&csum[su * 8 + i], s4);
    }
}

__global__ void k_final(const float* __restrict__ ws_csum, float* __restrict__ out_c) {
    int t = threadIdx.x;  // 0..63 -> c1, 64..127 -> c2
    float m = ws_csum[t] * (1.0f / (float)N_NODES);
    out_c[t] = 1.f / (1.f + expf(-m));
}

extern "C" void kernel_launch(void* const* d_in, const int* in_sizes, int n_in,
                              void* d_out, int out_size, void* d_ws, size_t ws_size,
                              hipStream_t stream) {
    const float* feat = (const float*)d_in[0];
    const float* shuf = (const float*)d_in[1];
    const int* src1 = (const int*)d_in[2];
    const int* dst1 = (const int*)d_in[3];
    const int* src2 = (const int*)d_in[4];
    const int* dst2 = (const int*)d_in[5];
    const float* W1 = (const float*)d_in[6];
    const float* b1 = (const float*)d_in[7];
    const float* W2 = (const float*)d_in[8];
    const float* b2 = (const float*)d_in[9];

    float* out = (float*)d_out;
    int* ws = (int*)d_ws;
    float* ws_f = (float*)d_ws;
    float* c_out = out + 2 * ND;

    k_init<<<1, 256, 0, stream>>>(ws);
    k_bhist_transform<<<BT_BLOCKS, 256, 0, stream>>>(
        (const int4*)dst1, (const int4*)dst2, ws, feat, shuf, W1, W2);
    k_bscan<<<1, 256, 0, stream>>>(ws);
    k_partition<<<dim3((N_EDGES / 4 + 511) / 512, 2), 256, 0, stream>>>(
        (const int4*)src1, (const int4*)dst1, (const int4*)src2, (const int4*)dst2, ws);
    k_place<<<dim3(NBUCK, 2), 256, 0, stream>>>(ws);
    k_gather_pre<<<dim3((N_NODES + 31) / 32, 2), 256, 0, stream>>>(ws, b1, b2, out);
    k_final<<<1, 128, 0, stream>>>(ws_f + WS_CSUM, c_out);
}

// Round 11
// 330.758 us; speedup vs baseline: 7.5995x; 1.0605x over previous
//
#include <hip/hip_runtime.h>
#include <hip/hip_bf16.h>

#define N_NODES 100000
#define N_EDGES 1000000
#define DIM 64

static const long long ND = (long long)N_NODES * DIM;  // 6,400,000

typedef float f4_t __attribute__((ext_vector_type(4)));

// d_out layout (floats):
// h1: [0, ND)  h2: [ND, 2*ND)  c1c2: [2*ND, 2*ND+128)  h3: [2*ND+128, ...)  h4: [3*ND+128, ...)

// d_ws layout (4-byte words):
#define WS_OFF1  200000            // 100001 used (region padded)
#define WS_OFF2  300004
#define WS_SORT1 400008            // payload (partition) then sorted src ids (place), 1M
#define WS_SORT2 1400008
#define WS_CSUM  2400008           // 128 floats
#define WS_BSUM  2400136           // 196: bucket counts -> exclusive bases
#define WS_BCUR  2400332           // 196: partition cursors
// planar bf16 tables, 32 words (64 bf16) per node row:
#define WS_T1G   2400640
#define WS_T1S   (WS_T1G + 3200000)
#define WS_T2G   (WS_T1G + 6400000)
#define WS_T2S   (WS_T1G + 9600000)
#define WS_END   (WS_T1G + 12800000) // 15,200,640 words ~= 58 MB (proven available)

#define NBUCK 98                   // buckets of 1024 nodes; 98*1024 >= 100000
#define PLACE_CAP 13312            // max bucket edges held in LDS (mean 10240, sd ~101)

// fused bucket-hist + transform grid: groups of 9 = 4 transform + 5 hist
#define BT_GROUPS 196              // transform: 196*4=784 blocks x 256 units >= 200000
#define BT_BLOCKS (BT_GROUPS * 9)

__device__ __forceinline__ float bf_lo(unsigned u) { return __uint_as_float(u << 16); }
__device__ __forceinline__ float bf_hi(unsigned u) { return __uint_as_float(u & 0xFFFF0000u); }

__global__ __launch_bounds__(256) void k_init(int* __restrict__ ws) {
    const int t = threadIdx.x;
    if (t < 128) ((float*)ws)[WS_CSUM + t] = 0.f;
    if (t < 196) ws[WS_BSUM + t] = 0;
    if (t == 0) {
        ws[WS_OFF1 + N_NODES] = N_EDGES;
        ws[WS_OFF2 + N_NODES] = N_EDGES;
    }
}

// FUSED bucket-hist + transform. Block role by blockIdx.x % 9: r<4 transform, r>=4 hist.
// Transform: lane j holds W1[:,j], W2[:,j] in regs (128 VGPR); 256 input rows
// staged in 64KB LDS; per row 16 broadcast ds_read_b128 + 128 FMA; bf16 store
// coalesced (lane j -> half-word j of the row). NO min-waves in launch_bounds
// (R7 lesson: (256,4) capped VGPR at 64 -> 7GB spill traffic).
__global__ __launch_bounds__(256) void k_bhist_transform(
    const int4* __restrict__ dst1, const int4* __restrict__ dst2,
    int* __restrict__ ws,
    const float* __restrict__ feat, const float* __restrict__ shuf,
    const float* __restrict__ W1, const float* __restrict__ W2) {
    __shared__ float At[256 * 64];           // 64KB; hist aliases the front as int[]
    const int grp = blockIdx.x / 9;
    const int r = blockIdx.x - grp * 9;
    const int t = threadIdx.x;

    if (r < 4) {
        // ---------------- transform ----------------
        const int u0 = (grp * 4 + r) * 256;  // unit = row index into [feat; shuf] (2*N)
        if (u0 >= 2 * N_NODES) return;
        const int lane = t & 63;
        const int wave = t >> 6;

        float w1c[64], w2c[64];
        #pragma unroll
        for (int k = 0; k < 64; ++k) {
            w1c[k] = W1[k * 64 + lane];
            w2c[k] = W2[k * 64 + lane];
        }

        // stage 256 rows (coalesced f4 loads)
        for (int q = t; q < 4096; q += 256) {
            const int row = q >> 4;
            const int u = u0 + row;
            f4_t v = {0.f, 0.f, 0.f, 0.f};
            if (u < 2 * N_NODES) {
                const float* sp = (u < N_NODES) ? feat + (long long)u * DIM
                                                : shuf + (long long)(u - N_NODES) * DIM;
                v = __builtin_nontemporal_load((const f4_t*)sp + (q & 15));
            }
            *(f4_t*)&At[q * 4] = v;
        }
        __syncthreads();

        const int rbeg = wave * 64;
        for (int rr = 0; rr < 64; ++rr) {
            const int row = rbeg + rr;
            const int u = u0 + row;
            if (u >= 2 * N_NODES) break;
            const float* ap = &At[row * 64];
            float acc1 = 0.f, acc2 = 0.f;
            #pragma unroll
            for (int k4 = 0; k4 < 16; ++k4) {
                const f4_t a = *(const f4_t*)(ap + 4 * k4);   // broadcast read
                acc1 += a.x * w1c[4 * k4] + a.y * w1c[4 * k4 + 1]
                      + a.z * w1c[4 * k4 + 2] + a.w * w1c[4 * k4 + 3];
                acc2 += a.x * w2c[4 * k4] + a.y * w2c[4 * k4 + 1]
                      + a.z * w2c[4 * k4 + 2] + a.w * w2c[4 * k4 + 3];
            }
            const bool isf = u < N_NODES;
            const long long n = isf ? u : u - N_NODES;
            __hip_bfloat16* d1 = (__hip_bfloat16*)(ws + (isf ? WS_T1G : WS_T1S)) + n * 64 + lane;
            __hip_bfloat16* d2 = (__hip_bfloat16*)(ws + (isf ? WS_T2G : WS_T2S)) + n * 64 + lane;
            *d1 = __float2bfloat16(acc1);
            *d2 = __float2bfloat16(acc2);
        }
    } else {
        // ---------------- bucket hist (LDS-privatized) ----------------
        int* lcnt = (int*)At;                 // 2*NBUCK ints
        for (int i = t; i < 2 * NBUCK; i += 256) lcnt[i] = 0;
        __syncthreads();
        const int Q = N_EDGES / 4;
        const int qb = (grp * 5 + (r - 4)) * 512;
        #pragma unroll
        for (int k = 0; k < 2; ++k) {
            const int q = qb + k * 256 + t;
            if (q < 2 * Q) {
                const int4 d = (q < Q) ? dst1[q] : dst2[q - Q];
                const int gb = (q < Q) ? 0 : NBUCK;
                atomicAdd(&lcnt[gb + (d.x >> 10)], 1);
                atomicAdd(&lcnt[gb + (d.y >> 10)], 1);
                atomicAdd(&lcnt[gb + (d.z >> 10)], 1);
                atomicAdd(&lcnt[gb + (d.w >> 10)], 1);
            }
        }
        __syncthreads();
        if (t < 2 * NBUCK && lcnt[t] != 0) atomicAdd(&ws[WS_BSUM + t], lcnt[t]);
    }
}

// Segmented exclusive scan of the 2x98 bucket counts (in place) + copy to cursors.
__global__ __launch_bounds__(256) void k_bscan(int* __restrict__ ws) {
    const int t = threadIdx.x;
    const int n = 2 * NBUCK;
    __shared__ int s[256];
    s[t] = (t < n) ? ws[WS_BSUM + t] : 0;
    __syncthreads();
    for (int d = 1; d < 256; d <<= 1) {
        int v = 0;
        if (t >= d && (t < NBUCK || t - d >= NBUCK)) v = s[t - d];
        __syncthreads();
        s[t] += v;
        __syncthreads();
    }
    if (t < n) {
        const int excl = (t == 0 || t == NBUCK) ? 0 : s[t - 1];
        ws[WS_BSUM + t] = excl;
        ws[WS_BCUR + t] = excl;
    }
}

// Partition: scatter packed payloads (src | dstlocal<<17) into SORT grouped by
// bucket, via block-level range reservation (dense per-block runs -> L2-friendly).
__global__ __launch_bounds__(256) void k_partition(
    const int4* __restrict__ src1, const int4* __restrict__ dst1,
    const int4* __restrict__ src2, const int4* __restrict__ dst2,
    int* __restrict__ ws) {
    const int g = blockIdx.y;
    const int t = threadIdx.x;
    __shared__ int lcnt[NBUCK];
    __shared__ int lbase[NBUCK];
    const int4* sv4 = g ? src2 : src1;
    const int4* dv4 = g ? dst2 : dst1;
    int* sortp = ws + (g ? WS_SORT2 : WS_SORT1);
    int* bcur = ws + WS_BCUR + g * NBUCK;
    const int Q = N_EDGES / 4;

    const int q0 = blockIdx.x * 512 + t;
    const int q1 = q0 + 256;
    const bool v0 = q0 < Q, v1 = q1 < Q;
    int4 s0, d0, s1, d1;
    if (v0) { s0 = sv4[q0]; d0 = dv4[q0]; }
    if (v1) { s1 = sv4[q1]; d1 = dv4[q1]; }

    for (int i = t; i < NBUCK; i += 256) lcnt[i] = 0;
    __syncthreads();
    if (v0) {
        atomicAdd(&lcnt[d0.x >> 10], 1); atomicAdd(&lcnt[d0.y >> 10], 1);
        atomicAdd(&lcnt[d0.z >> 10], 1); atomicAdd(&lcnt[d0.w >> 10], 1);
    }
    if (v1) {
        atomicAdd(&lcnt[d1.x >> 10], 1); atomicAdd(&lcnt[d1.y >> 10], 1);
        atomicAdd(&lcnt[d1.z >> 10], 1); atomicAdd(&lcnt[d1.w >> 10], 1);
    }
    __syncthreads();
    if (t < NBUCK) lbase[t] = lcnt[t] ? atomicAdd(&bcur[t], lcnt[t]) : 0;
    __syncthreads();

#define PUT(ss, dd) { const int b_ = (dd) >> 10; \
    const int pos_ = atomicAdd(&lbase[b_], 1); \
    sortp[pos_] = (ss) | (((dd) & 1023) << 17); }
    if (v0) { PUT(s0.x, d0.x); PUT(s0.y, d0.y); PUT(s0.z, d0.z); PUT(s0.w, d0.w); }
    if (v1) { PUT(s1.x, d1.x); PUT(s1.y, d1.y); PUT(s1.z, d1.z); PUT(s1.w, d1.w); }
#undef PUT
}

// Place: one block per (bucket, graph). Load bucket payloads fully into LDS,
// local per-node hist + exclusive scan -> off[], then in-place scatter of src
// ids within the bucket's contiguous (L2-resident) window.
__global__ __launch_bounds__(256) void k_place(int* __restrict__ ws) {
    const int g = blockIdx.y;
    const int b = blockIdx.x;
    const int t = threadIdx.x;
    __shared__ int pl[PLACE_CAP];
    __shared__ int lcur[1024];
    __shared__ int sscan[256];

    const int base = ws[WS_BSUM + g * NBUCK + b];
    const int end = (b == NBUCK - 1) ? N_EDGES : ws[WS_BSUM + g * NBUCK + b + 1];
    int cnt = end - base;
    if (cnt > PLACE_CAP) cnt = PLACE_CAP;   // safety clamp (30-sigma margin, never hit)
    int* sortp = ws + (g ? WS_SORT2 : WS_SORT1);
    int* off = ws + (g ? WS_OFF2 : WS_OFF1);
    const int node0 = b << 10;

    for (int i = t; i < cnt; i += 256) pl[i] = sortp[base + i];
    for (int i = t; i < 1024; i += 256) lcur[i] = 0;
    __syncthreads();
    for (int i = t; i < cnt; i += 256) atomicAdd(&lcur[(pl[i] >> 17) & 1023], 1);
    __syncthreads();

    const int c0 = lcur[4 * t], c1 = lcur[4 * t + 1], c2 = lcur[4 * t + 2], c3 = lcur[4 * t + 3];
    sscan[t] = c0 + c1 + c2 + c3;
    __syncthreads();
    for (int d = 1; d < 256; d <<= 1) {
        int v = 0;
        if (t >= d) v = sscan[t - d];
        __syncthreads();
        sscan[t] += v;
        __syncthreads();
    }
    const int excl = (t == 0) ? 0 : sscan[t - 1];
    const int p0 = base + excl, p1 = p0 + c0, p2 = p1 + c1, p3 = p2 + c2;
    lcur[4 * t] = p0; lcur[4 * t + 1] = p1; lcur[4 * t + 2] = p2; lcur[4 * t + 3] = p3;
    const int idx = node0 + 4 * t;
    if (idx + 3 < N_NODES) {
        *(int4*)(off + idx) = make_int4(p0, p1, p2, p3);
    } else {
        if (idx + 0 < N_NODES) off[idx + 0] = p0;
        if (idx + 1 < N_NODES) off[idx + 1] = p1;
        if (idx + 2 < N_NODES) off[idx + 2] = p2;
        if (idx + 3 < N_NODES) off[idx + 3] = p3;
    }
    __syncthreads();
    for (int i = t; i < cnt; i += 256) {
        const int p = pl[i];
        const int pos = atomicAdd(&lcur[(p >> 17) & 1023], 1);
        sortp[pos] = p & 0x1FFFF;
    }
}

// Gather-aggregate, both graphs (blockIdx.y = graph). One node per 8-lane group,
// 8 nodes/wave concurrent. Lane sub owns dims [8sub,8sub+8) of G and S planes.
// Unroll-4 edge loop -> 8 independent 16B loads in flight per lane.
#define ACC2(gv, sv) \
    ag[0] += bf_lo(gv.x); ag[1] += bf_hi(gv.x); \
    ag[2] += bf_lo(gv.y); ag[3] += bf_hi(gv.y); \
    ag[4] += bf_lo(gv.z); ag[5] += bf_hi(gv.z); \
    ag[6] += bf_lo(gv.w); ag[7] += bf_hi(gv.w); \
    as[0] += bf_lo(sv.x); as[1] += bf_hi(sv.x); \
    as[2] += bf_lo(sv.y); as[3] += bf_hi(sv.y); \
    as[4] += bf_lo(sv.z); as[5] += bf_hi(sv.z); \
    as[6] += bf_lo(sv.w); as[7] += bf_hi(sv.w);

__global__ __launch_bounds__(256) void k_gather_pre(int* __restrict__ ws,
                                                    const float* __restrict__ b1,
                                                    const float* __restrict__ b2,
                                                    float* __restrict__ out) {
    const int g = blockIdx.y;
    const int* off    = ws + (g ? WS_OFF2 : WS_OFF1);
    const int* sorted = ws + (g ? WS_SORT2 : WS_SORT1);
    const uint4* TG = (const uint4*)(ws + (g ? WS_T2G : WS_T1G));  // 8 uint4/row
    const uint4* TS = (const uint4*)(ws + (g ? WS_T2S : WS_T1S));
    const float* bias = g ? b2 : b1;
    float* h_f = out + (g ? ND : 0);
    float* h_s = out + (g ? 3 * ND + 128 : 2 * ND + 128);
    float* csum = (float*)ws + WS_CSUM + g * 64;

    const int t = threadIdx.x;
    const int wave = t >> 6;
    const int lane = t & 63;
    const int nslot = lane >> 3;
    const int sub = lane & 7;

    float bias8[8];
    #pragma unroll
    for (int i = 0; i < 8; ++i) bias8[i] = bias[sub * 8 + i];

    float ag[8] = {0.f, 0.f, 0.f, 0.f, 0.f, 0.f, 0.f, 0.f};
    float as[8] = {0.f, 0.f, 0.f, 0.f, 0.f, 0.f, 0.f, 0.f};

    const int n = blockIdx.x * 32 + wave * 8 + nslot;
    if (n < N_NODES) {
        const int e0 = off[n];
        const int e1 = off[n + 1];
        int e = e0;
        for (; e + 3 < e1; e += 4) {
            const int sA = sorted[e], sB = sorted[e + 1];
            const int sC = sorted[e + 2], sD = sorted[e + 3];
            const uint4 gA = TG[sA * 8 + sub], hA = TS[sA * 8 + sub];
            const uint4 gB = TG[sB * 8 + sub], hB = TS[sB * 8 + sub];
            const uint4 gC = TG[sC * 8 + sub], hC = TS[sC * 8 + sub];
            const uint4 gD = TG[sD * 8 + sub], hD = TS[sD * 8 + sub];
            ACC2(gA, hA); ACC2(gB, hB); ACC2(gC, hC); ACC2(gD, hD);
        }
        for (; e < e1; ++e) {
            const int s = sorted[e];
            const uint4 gv = TG[s * 8 + sub], hv = TS[s * 8 + sub];
            ACC2(gv, hv);
        }
        #pragma unroll
        for (int i = 0; i < 8; ++i) {
            ag[i] += bias8[i];
            as[i] += bias8[i];
        }
        float* pf = h_f + (long long)n * DIM + sub * 8;
        f4_t v0 = {ag[0], ag[1], ag[2], ag[3]};
        f4_t v1 = {ag[4], ag[5], ag[6], ag[7]};
        __builtin_nontemporal_store(v0, (f4_t*)pf);
        __builtin_nontemporal_store(v1, (f4_t*)(pf + 4));
        float* ps = h_s + (long long)n * DIM + sub * 8;
        f4_t u0 = {as[0], as[1], as[2], as[3]};
        f4_t u1 = {as[4], as[5], as[6], as[7]};
        __builtin_nontemporal_store(u0, (f4_t*)ps);
        __builtin_nontemporal_store(u1, (f4_t*)(ps + 4));
    } else {
        #pragma unroll
        for (int i = 0; i < 8; ++i) ag[i] = 0.f;
    }

    // csum (feat branch): reduce ag across the wave's 8 node-slots
    __shared__ float red[4][8][8];
    #pragma unroll
    for (int i = 0; i < 8; ++i) {
        float v = ag[i];
        v += __shfl_xor(v, 8);
        v += __shfl_xor(v, 16);
        v += __shfl_xor(v, 32);
        if (lane < 8) red[wave][sub][i] = v;
    }
    __syncthreads();
    if (t < 64) {
        const int su = t >> 3, i = t & 7;
        const float s4 = red[0][su][i] + red[1][su][i] + red[2][su][i] + red[3][su][i];
        unsafeAtomicAdd(&csum[su * 8 + i], s4);
    }
}

__global__ void k_final(const float* __restrict__ ws_csum, float* __restrict__ out_c) {
    int t = threadIdx.x;  // 0..63 -> c1, 64..127 -> c2
    float m = ws_csum[t] * (1.0f / (float)N_NODES);
    out_c[t] = 1.f / (1.f + expf(-m));
}

extern "C" void kernel_launch(void* const* d_in, const int* in_sizes, int n_in,
                              void* d_out, int out_size, void* d_ws, size_t ws_size,
                              hipStream_t stream) {
    const float* feat = (const float*)d_in[0];
    const float* shuf = (const float*)d_in[1];
    const int* src1 = (const int*)d_in[2];
    const int* dst1 = (const int*)d_in[3];
    const int* src2 = (const int*)d_in[4];
    const int* dst2 = (const int*)d_in[5];
    const float* W1 = (const float*)d_in[6];
    const float* b1 = (const float*)d_in[7];
    const float* W2 = (const float*)d_in[8];
    const float* b2 = (const float*)d_in[9];

    float* out = (float*)d_out;
    int* ws = (int*)d_ws;
    float* ws_f = (float*)d_ws;
    float* c_out = out + 2 * ND;

    k_init<<<1, 256, 0, stream>>>(ws);
    k_bhist_transform<<<BT_BLOCKS, 256, 0, stream>>>(
        (const int4*)dst1, (const int4*)dst2, ws, feat, shuf, W1, W2);
    k_bscan<<<1, 256, 0, stream>>>(ws);
    k_partition<<<dim3((N_EDGES / 4 + 511) / 512, 2), 256, 0, stream>>>(
        (const int4*)src1, (const int4*)dst1, (const int4*)src2, (const int4*)dst2, ws);
    k_place<<<dim3(NBUCK, 2), 256, 0, stream>>>(ws);
    k_gather_pre<<<dim3((N_NODES + 31) / 32, 2), 256, 0, stream>>>(ws, b1, b2, out);
    k_final<<<1, 128, 0, stream>>>(ws_f + WS_CSUM, c_out);
}